// Round 1
// baseline (1050.759 us; speedup 1.0000x reference)
//
#include <hip/hip_runtime.h>

#define N_NODES 100000
#define N_HEDGES 30000
#define N_PINS 400000

// ---------------------------------------------------------------------------
// prep: Vv[b][d][c] = Vw[b][c/32][d][c%32]  (c = h*32+k head-concat layout)
//       qv[b][d][h] = sum_k Kw[b][h][d][k] * Qw[b][h][k]
// ---------------------------------------------------------------------------
__global__ __launch_bounds__(256) void prep_weights(
    const float* __restrict__ Vw, const float* __restrict__ Kw,
    const float* __restrict__ Qw, float* __restrict__ Vv, float* __restrict__ qv) {
  int i = blockIdx.x * 256 + threadIdx.x;
  if (i < 4 * 128 * 128) {
    int b = i >> 14, r = i & 16383, d = r >> 7, c = r & 127;
    int h = c >> 5, k = c & 31;
    Vv[i] = Vw[((b * 4 + h) * 128 + d) * 32 + k];
  }
  if (i < 4 * 128 * 4) {
    int b = i >> 9, r = i & 511, d = r >> 2, h = r & 3;
    const float* kw = Kw + ((b * 4 + h) * 128 + d) * 32;
    const float* qw = Qw + (b * 4 + h) * 32;
    float s = 0.f;
    for (int k = 0; k < 32; ++k) s += kw[k] * qw[k];
    qv[i] = s;
  }
}

// ---------------------------------------------------------------------------
// CSR build: counts, block-aggregated-atomic exclusive scan, fill
// ---------------------------------------------------------------------------
__global__ __launch_bounds__(256) void csr_count(
    const int* __restrict__ node_idx, const int* __restrict__ hedge_idx,
    int* __restrict__ cntN, int* __restrict__ cntH) {
  int e = blockIdx.x * 256 + threadIdx.x;
  if (e < N_PINS) {
    atomicAdd(&cntN[node_idx[e]], 1);
    atomicAdd(&cntH[hedge_idx[e]], 1);
  }
}

__global__ __launch_bounds__(256) void csr_scan(
    const int* __restrict__ cnt, int* __restrict__ start, int n, int* gctr) {
  __shared__ int wsum[4];
  __shared__ int bbase;
  int i = blockIdx.x * 256 + threadIdx.x;
  int lane = threadIdx.x & 63, wid = threadIdx.x >> 6;
  int v = (i < n) ? cnt[i] : 0;
  int sc = v;
#pragma unroll
  for (int s = 1; s < 64; s <<= 1) {
    int tv = __shfl_up(sc, s);
    if (lane >= s) sc += tv;
  }
  if (lane == 63) wsum[wid] = sc;
  __syncthreads();
  if (threadIdx.x == 0) {
    int s0 = wsum[0], s1 = wsum[1], s2 = wsum[2], s3 = wsum[3];
    wsum[0] = 0; wsum[1] = s0; wsum[2] = s0 + s1; wsum[3] = s0 + s1 + s2;
    bbase = atomicAdd(gctr, s0 + s1 + s2 + s3);
  }
  __syncthreads();
  if (i < n) start[i] = bbase + wsum[wid] + (sc - v);
}

__global__ __launch_bounds__(256) void csr_fill(
    const int* __restrict__ node_idx, const int* __restrict__ hedge_idx,
    const int* __restrict__ startN, const int* __restrict__ startH,
    int* __restrict__ fillN, int* __restrict__ fillH,
    int* __restrict__ pinsN, int* __restrict__ pinsH) {
  int e = blockIdx.x * 256 + threadIdx.x;
  if (e < N_PINS) {
    int n = node_idx[e], h = hedge_idx[e];
    int pH = startH[h] + atomicAdd(&fillH[h], 1);
    pinsH[pH] = n;  // per-hedge list of source nodes   (vertex->edge blocks)
    int pN = startN[n] + atomicAdd(&fillN[n], 1);
    pinsN[pN] = h;  // per-node list of source hedges   (edge->vertex blocks)
  }
}

// ---------------------------------------------------------------------------
// transform: Vx[n][128] = x[n]·Vv ;  lg[n][4] = x[n]·qv.  8 rows / block.
// ---------------------------------------------------------------------------
__global__ __launch_bounds__(256) void transform_k(
    const float* __restrict__ x, const float* __restrict__ Vv,
    const float* __restrict__ qv, float* __restrict__ Vx,
    float* __restrict__ lg, int n_src) {
  __shared__ float xs[8][128];
  int t = threadIdx.x;
  int r0 = blockIdx.x * 8;
  ((float4*)xs)[t] = ((const float4*)(x + (size_t)r0 * 128))[t];
  __syncthreads();
  int c = t & 127, rg = t >> 7;
  float a0 = 0.f, a1 = 0.f, a2 = 0.f, a3 = 0.f;
  for (int d = 0; d < 128; d += 4) {
    float w0 = Vv[d * 128 + c], w1 = Vv[(d + 1) * 128 + c];
    float w2 = Vv[(d + 2) * 128 + c], w3 = Vv[(d + 3) * 128 + c];
    float4 xv;
    xv = *(const float4*)&xs[rg * 4 + 0][d]; a0 += xv.x * w0 + xv.y * w1 + xv.z * w2 + xv.w * w3;
    xv = *(const float4*)&xs[rg * 4 + 1][d]; a1 += xv.x * w0 + xv.y * w1 + xv.z * w2 + xv.w * w3;
    xv = *(const float4*)&xs[rg * 4 + 2][d]; a2 += xv.x * w0 + xv.y * w1 + xv.z * w2 + xv.w * w3;
    xv = *(const float4*)&xs[rg * 4 + 3][d]; a3 += xv.x * w0 + xv.y * w1 + xv.z * w2 + xv.w * w3;
  }
  int rb = r0 + rg * 4;
  Vx[(size_t)(rb + 0) * 128 + c] = a0;
  Vx[(size_t)(rb + 1) * 128 + c] = a1;
  Vx[(size_t)(rb + 2) * 128 + c] = a2;
  Vx[(size_t)(rb + 3) * 128 + c] = a3;
  // logits: 32 lanes per row, 4 heads
  int rr = t >> 5, lc = t & 31;
  float p0 = 0.f, p1 = 0.f, p2 = 0.f, p3 = 0.f;
#pragma unroll
  for (int j = 0; j < 4; ++j) {
    int d = lc + 32 * j;
    float xv = xs[rr][d];
    float4 q4 = *(const float4*)&qv[d * 4];
    p0 += xv * q4.x; p1 += xv * q4.y; p2 += xv * q4.z; p3 += xv * q4.w;
  }
#pragma unroll
  for (int off = 1; off < 32; off <<= 1) {
    p0 += __shfl_xor(p0, off); p1 += __shfl_xor(p1, off);
    p2 += __shfl_xor(p2, off); p3 += __shfl_xor(p3, off);
  }
  if (lc == 0) {
    float* o = lg + (size_t)(r0 + rr) * 4;
    o[0] = p0; o[1] = p1; o[2] = p2; o[3] = p3;
  }
}

// ---------------------------------------------------------------------------
// attention: wave per target. two-pass segment softmax + weighted Vx gather,
// + Q-skip + LN0.  xmid[t][128] output.
// ---------------------------------------------------------------------------
__global__ __launch_bounds__(256) void attn_k(
    const float* __restrict__ Vx, const float* __restrict__ lg,
    const int* __restrict__ start, const int* __restrict__ cnt,
    const int* __restrict__ pins, const float* __restrict__ Qflat,
    const float* __restrict__ g0, const float* __restrict__ be0,
    float* __restrict__ xmid, int n_tgt) {
  int wid = threadIdx.x >> 6, lane = threadIdx.x & 63;
  int tg = blockIdx.x * 4 + wid;
  if (tg >= n_tgt) return;
  int base = start[tg], deg = cnt[tg];
  int h = lane & 3;
  float m = -3.4e38f;
  for (int i = lane >> 2; i < deg; i += 16) {
    int s = pins[base + i];
    m = fmaxf(m, lg[(size_t)s * 4 + h]);
  }
  m = fmaxf(m, __shfl_xor(m, 4));
  m = fmaxf(m, __shfl_xor(m, 8));
  m = fmaxf(m, __shfl_xor(m, 16));
  m = fmaxf(m, __shfl_xor(m, 32));
  float den = 0.f;
  for (int i = lane >> 2; i < deg; i += 16) {
    int s = pins[base + i];
    den += __expf(lg[(size_t)s * 4 + h] - m);
  }
  den += __shfl_xor(den, 4);
  den += __shfl_xor(den, 8);
  den += __shfl_xor(den, 16);
  den += __shfl_xor(den, 32);
  int h0 = lane >> 5;  // head for d=lane; head for d=lane+64 is h0+2
  float m0 = __shfl(m, h0), m1 = __shfl(m, h0 + 2);
  float d0 = __shfl(den, h0), d1 = __shfl(den, h0 + 2);
  float rd0 = (deg > 0) ? 1.f / d0 : 0.f;
  float rd1 = (deg > 0) ? 1.f / d1 : 0.f;
  float acc0 = 0.f, acc1 = 0.f;
  for (int e = 0; e < deg; ++e) {
    int s = pins[base + e];
    const float* vrow = Vx + (size_t)s * 128;
    float w0 = __expf(lg[(size_t)s * 4 + h0] - m0) * rd0;
    float w1 = __expf(lg[(size_t)s * 4 + h0 + 2] - m1) * rd1;
    acc0 += w0 * vrow[lane];
    acc1 += w1 * vrow[lane + 64];
  }
  float x0v = acc0 + Qflat[lane];
  float x1v = acc1 + Qflat[lane + 64];
  float s1 = x0v + x1v, s2 = x0v * x0v + x1v * x1v;
#pragma unroll
  for (int off = 1; off < 64; off <<= 1) {
    s1 += __shfl_xor(s1, off);
    s2 += __shfl_xor(s2, off);
  }
  float mean = s1 * (1.f / 128.f);
  float var = s2 * (1.f / 128.f) - mean * mean;
  float rs = rsqrtf(var + 1e-5f);
  float* o = xmid + (size_t)tg * 128;
  o[lane] = (x0v - mean) * rs * g0[lane] + be0[lane];
  o[lane + 64] = (x1v - mean) * rs * g0[lane + 64] + be0[lane + 64];
}

// ---------------------------------------------------------------------------
// mlp: h=relu(x@W1+b1)@W2+b2 ; out=relu(LN1(x+h)).  8 rows / block.
// ---------------------------------------------------------------------------
__global__ __launch_bounds__(256) void mlp_k(
    const float* __restrict__ xin, const float* __restrict__ W1,
    const float* __restrict__ b1, const float* __restrict__ W2,
    const float* __restrict__ b2, const float* __restrict__ g1,
    const float* __restrict__ be1, float* __restrict__ out, int n) {
  __shared__ float xs[8][128];
  __shared__ float h1[8][128];
  int t = threadIdx.x;
  int r0 = blockIdx.x * 8;
  ((float4*)xs)[t] = ((const float4*)(xin + (size_t)r0 * 128))[t];
  __syncthreads();
  int c = t & 127, rg = t >> 7;
  float a0, a1, a2, a3;
  {
    float bb = b1[c];
    a0 = a1 = a2 = a3 = bb;
    for (int d = 0; d < 128; d += 4) {
      float w0 = W1[d * 128 + c], w1 = W1[(d + 1) * 128 + c];
      float w2 = W1[(d + 2) * 128 + c], w3 = W1[(d + 3) * 128 + c];
      float4 xv;
      xv = *(const float4*)&xs[rg * 4 + 0][d]; a0 += xv.x * w0 + xv.y * w1 + xv.z * w2 + xv.w * w3;
      xv = *(const float4*)&xs[rg * 4 + 1][d]; a1 += xv.x * w0 + xv.y * w1 + xv.z * w2 + xv.w * w3;
      xv = *(const float4*)&xs[rg * 4 + 2][d]; a2 += xv.x * w0 + xv.y * w1 + xv.z * w2 + xv.w * w3;
      xv = *(const float4*)&xs[rg * 4 + 3][d]; a3 += xv.x * w0 + xv.y * w1 + xv.z * w2 + xv.w * w3;
    }
  }
  h1[rg * 4 + 0][c] = fmaxf(a0, 0.f);
  h1[rg * 4 + 1][c] = fmaxf(a1, 0.f);
  h1[rg * 4 + 2][c] = fmaxf(a2, 0.f);
  h1[rg * 4 + 3][c] = fmaxf(a3, 0.f);
  __syncthreads();
  {
    float bb = b2[c];
    a0 = a1 = a2 = a3 = bb;
    for (int d = 0; d < 128; d += 4) {
      float w0 = W2[d * 128 + c], w1 = W2[(d + 1) * 128 + c];
      float w2 = W2[(d + 2) * 128 + c], w3 = W2[(d + 3) * 128 + c];
      float4 xv;
      xv = *(const float4*)&h1[rg * 4 + 0][d]; a0 += xv.x * w0 + xv.y * w1 + xv.z * w2 + xv.w * w3;
      xv = *(const float4*)&h1[rg * 4 + 1][d]; a1 += xv.x * w0 + xv.y * w1 + xv.z * w2 + xv.w * w3;
      xv = *(const float4*)&h1[rg * 4 + 2][d]; a2 += xv.x * w0 + xv.y * w1 + xv.z * w2 + xv.w * w3;
      xv = *(const float4*)&h1[rg * 4 + 3][d]; a3 += xv.x * w0 + xv.y * w1 + xv.z * w2 + xv.w * w3;
    }
  }
  // residual y = x + h, in place over xs (GEMM1 xs-reads completed at barrier)
  xs[rg * 4 + 0][c] += a0;
  xs[rg * 4 + 1][c] += a1;
  xs[rg * 4 + 2][c] += a2;
  xs[rg * 4 + 3][c] += a3;
  __syncthreads();
  // LN1 + relu: 32 lanes per row
  int rr = t >> 5, lc = t & 31;
  float v0 = xs[rr][lc], v1 = xs[rr][lc + 32], v2 = xs[rr][lc + 64], v3 = xs[rr][lc + 96];
  float s1 = v0 + v1 + v2 + v3;
  float s2 = v0 * v0 + v1 * v1 + v2 * v2 + v3 * v3;
#pragma unroll
  for (int off = 1; off < 32; off <<= 1) {
    s1 += __shfl_xor(s1, off);
    s2 += __shfl_xor(s2, off);
  }
  float mean = s1 * (1.f / 128.f);
  float var = s2 * (1.f / 128.f) - mean * mean;
  float rs = rsqrtf(var + 1e-5f);
  float* o = out + (size_t)(r0 + rr) * 128;
  o[lc]      = fmaxf((v0 - mean) * rs * g1[lc]      + be1[lc],      0.f);
  o[lc + 32] = fmaxf((v1 - mean) * rs * g1[lc + 32] + be1[lc + 32], 0.f);
  o[lc + 64] = fmaxf((v2 - mean) * rs * g1[lc + 64] + be1[lc + 64], 0.f);
  o[lc + 96] = fmaxf((v3 - mean) * rs * g1[lc + 96] + be1[lc + 96], 0.f);
}

// ---------------------------------------------------------------------------
extern "C" void kernel_launch(void* const* d_in, const int* in_sizes, int n_in,
                              void* d_out, int out_size, void* d_ws, size_t ws_size,
                              hipStream_t stream) {
  const float* x0_in = (const float*)d_in[0];
  const float* Kw  = (const float*)d_in[1];
  const float* Vw  = (const float*)d_in[2];
  const float* Qw  = (const float*)d_in[3];
  const float* W1  = (const float*)d_in[4];
  const float* b1  = (const float*)d_in[5];
  const float* W2  = (const float*)d_in[6];
  const float* b2  = (const float*)d_in[7];
  const float* ln0g = (const float*)d_in[8];
  const float* ln0b = (const float*)d_in[9];
  const float* ln1g = (const float*)d_in[10];
  const float* ln1b = (const float*)d_in[11];
  const int* node_idx  = (const int*)d_in[12];
  const int* hedge_idx = (const int*)d_in[13];

  float* out = (float*)d_out;
  float* x0_out = out;                          // [100000][128]
  float* x1_out = out + (size_t)N_NODES * 128;  // [30000][128]

  char* w = (char*)d_ws;
  auto alloc = [&](size_t bytes) -> void* {
    void* p = (void*)w;
    w += (bytes + 255) & ~(size_t)255;
    return p;
  };
  float* Vv   = (float*)alloc(4 * 128 * 128 * 4);
  float* qv   = (float*)alloc(4 * 128 * 4 * 4);
  float* Vx   = (float*)alloc((size_t)N_NODES * 128 * 4);
  float* lg   = (float*)alloc((size_t)N_NODES * 4 * 4);
  float* xmid = (float*)alloc((size_t)N_NODES * 128 * 4);
  int* startH = (int*)alloc(N_HEDGES * 4);
  int* startN = (int*)alloc(N_NODES * 4);
  int* pinsH  = (int*)alloc(N_PINS * 4);
  int* pinsN  = (int*)alloc(N_PINS * 4);
  // contiguous zero-init region: cntH, cntN, fillH, fillN, gctr[2]
  int* zbase = (int*)alloc((size_t)(N_HEDGES + N_NODES + N_HEDGES + N_NODES + 2) * 4);
  int* cntH = zbase;
  int* cntN = cntH + N_HEDGES;
  int* fillH = cntN + N_NODES;
  int* fillN = fillH + N_HEDGES;
  int* gctr = fillN + N_NODES;

  hipMemsetAsync(zbase, 0, (size_t)(2 * (N_HEDGES + N_NODES) + 2) * 4, stream);

  prep_weights<<<256, 256, 0, stream>>>(Vw, Kw, Qw, Vv, qv);
  csr_count<<<(N_PINS + 255) / 256, 256, 0, stream>>>(node_idx, hedge_idx, cntN, cntH);
  csr_scan<<<(N_HEDGES + 255) / 256, 256, 0, stream>>>(cntH, startH, N_HEDGES, gctr + 0);
  csr_scan<<<(N_NODES + 255) / 256, 256, 0, stream>>>(cntN, startN, N_NODES, gctr + 1);
  csr_fill<<<(N_PINS + 255) / 256, 256, 0, stream>>>(node_idx, hedge_idx, startN, startH,
                                                     fillN, fillH, pinsN, pinsH);

  // block schedule: src buf, n_src, CSR(start,cnt,pins), n_tgt, out buf
  const float* srcs[4] = {x0_in, x1_out, x0_out, x1_out};
  int n_srcs[4] = {N_NODES, N_HEDGES, N_NODES, N_HEDGES};
  const int* starts[4] = {startH, startN, startH, startN};
  const int* cnts[4] = {cntH, cntN, cntH, cntN};
  const int* pinss[4] = {pinsH, pinsN, pinsH, pinsN};
  int n_tgts[4] = {N_HEDGES, N_NODES, N_HEDGES, N_NODES};
  float* outs[4] = {x1_out, x0_out, x1_out, x0_out};

  for (int b = 0; b < 4; ++b) {
    int n_src = n_srcs[b], n_tgt = n_tgts[b];
    transform_k<<<n_src / 8, 256, 0, stream>>>(srcs[b], Vv + b * 16384, qv + b * 512,
                                               Vx, lg, n_src);
    attn_k<<<n_tgt / 4, 256, 0, stream>>>(Vx, lg, starts[b], cnts[b], pinss[b],
                                          Qw + b * 128, ln0g + b * 128, ln0b + b * 128,
                                          xmid, n_tgt);
    mlp_k<<<n_tgt / 8, 256, 0, stream>>>(xmid, W1 + b * 16384, b1 + b * 128,
                                         W2 + b * 16384, b2 + b * 128,
                                         ln1g + b * 128, ln1b + b * 128, outs[b], n_tgt);
  }
}

// Round 2
// 476.285 us; speedup vs baseline: 2.2062x; 2.2062x over previous
//
#include <hip/hip_runtime.h>

#define N_NODES 100000
#define N_HEDGES 30000
#define N_PINS 400000
#define NPN 100096   // padded node rows (>= 1563*64)
#define NPH 30080    // padded hedge rows (>= 469*64)

typedef __attribute__((ext_vector_type(8))) short bf16x8;
typedef __attribute__((ext_vector_type(4))) float f32x4;
typedef unsigned short ushort_t;

__device__ __forceinline__ unsigned short f2bf(float f) {
  unsigned int u = __float_as_uint(f);
  u += 0x7FFF + ((u >> 16) & 1);
  return (unsigned short)(u >> 16);
}
__device__ __forceinline__ float bf2f(unsigned short s) {
  return __uint_as_float(((unsigned int)s) << 16);
}
__device__ __forceinline__ void gload16(const void* g, void* l) {
  __builtin_amdgcn_global_load_lds(
      (const __attribute__((address_space(1))) unsigned int*)g,
      (__attribute__((address_space(3))) unsigned int*)l, 16, 0, 0);
}

// ---------------------------------------------------------------------------
// prep: build bf16, transposed, XOR-swizzled B-matrices.
//  Vvqsw[b]: 144 cols x 128 k. col c<128: Vw[b][c>>5][k][c&31]; c in 128..131:
//  qv[k][c-128] = sum_j Kw[b][h][k][j]*Qw[b][h][j]; else 0.
//  W1sw/W2sw[b]: 128 cols x 128 k = W[k][c] transposed.
//  byte layout within tile: L = c*256 + k*2, stored at L ^ ((c&7)<<4).
// ---------------------------------------------------------------------------
__global__ __launch_bounds__(256) void prep_k(
    const float* __restrict__ Kw, const float* __restrict__ Vw,
    const float* __restrict__ Qw, const float* __restrict__ W1,
    const float* __restrict__ W2, ushort_t* __restrict__ Vvqsw,
    ushort_t* __restrict__ W1sw, ushort_t* __restrict__ W2sw) {
  int i = blockIdx.x * 256 + threadIdx.x;
  if (i < 4 * 144 * 128) {
    int b = i / 18432, r = i % 18432, c = r >> 7, d = r & 127;
    float v;
    if (c < 128) {
      v = Vw[((b * 4 + (c >> 5)) * 128 + d) * 32 + (c & 31)];
    } else if (c < 132) {
      int h = c - 128;
      const float* kp = Kw + ((b * 4 + h) * 128 + d) * 32;
      const float* qp = Qw + (b * 4 + h) * 32;
      float s = 0.f;
      for (int k = 0; k < 32; ++k) s += kp[k] * qp[k];
      v = s;
    } else {
      v = 0.f;
    }
    int L = (c * 256 + d * 2) ^ ((c & 7) << 4);
    Vvqsw[b * 18432 + L / 2] = f2bf(v);
  }
  if (i < 4 * 128 * 128) {
    int b = i >> 14, r = i & 16383, c = r >> 7, k = r & 127;
    int L = (c * 256 + k * 2) ^ ((c & 7) << 4);
    int idx = b * 16384 + L / 2;
    W1sw[idx] = f2bf(W1[b * 16384 + k * 128 + c]);
    W2sw[idx] = f2bf(W2[b * 16384 + k * 128 + c]);
  }
}

// f32 -> bf16 bulk convert (4 elems/thread)
__global__ __launch_bounds__(256) void conv_k(const float* __restrict__ x,
                                              ushort_t* __restrict__ xb, int n4) {
  int i = blockIdx.x * 256 + threadIdx.x;
  if (i < n4) {
    float4 v = ((const float4*)x)[i];
    ushort_t o0 = f2bf(v.x), o1 = f2bf(v.y), o2 = f2bf(v.z), o3 = f2bf(v.w);
    ushort_t* p = xb + (size_t)i * 4;
    p[0] = o0; p[1] = o1; p[2] = o2; p[3] = o3;
  }
}

// ---------------------------------------------------------------------------
// CSR build (unchanged from round 1)
// ---------------------------------------------------------------------------
__global__ __launch_bounds__(256) void csr_count(
    const int* __restrict__ node_idx, const int* __restrict__ hedge_idx,
    int* __restrict__ cntN, int* __restrict__ cntH) {
  int e = blockIdx.x * 256 + threadIdx.x;
  if (e < N_PINS) {
    atomicAdd(&cntN[node_idx[e]], 1);
    atomicAdd(&cntH[hedge_idx[e]], 1);
  }
}

__global__ __launch_bounds__(256) void csr_scan(
    const int* __restrict__ cnt, int* __restrict__ start, int n, int* gctr) {
  __shared__ int wsum[4];
  __shared__ int bbase;
  int i = blockIdx.x * 256 + threadIdx.x;
  int lane = threadIdx.x & 63, wid = threadIdx.x >> 6;
  int v = (i < n) ? cnt[i] : 0;
  int sc = v;
#pragma unroll
  for (int s = 1; s < 64; s <<= 1) {
    int tv = __shfl_up(sc, s);
    if (lane >= s) sc += tv;
  }
  if (lane == 63) wsum[wid] = sc;
  __syncthreads();
  if (threadIdx.x == 0) {
    int s0 = wsum[0], s1 = wsum[1], s2 = wsum[2], s3 = wsum[3];
    wsum[0] = 0; wsum[1] = s0; wsum[2] = s0 + s1; wsum[3] = s0 + s1 + s2;
    bbase = atomicAdd(gctr, s0 + s1 + s2 + s3);
  }
  __syncthreads();
  if (i < n) start[i] = bbase + wsum[wid] + (sc - v);
}

__global__ __launch_bounds__(256) void csr_fill(
    const int* __restrict__ node_idx, const int* __restrict__ hedge_idx,
    const int* __restrict__ startN, const int* __restrict__ startH,
    int* __restrict__ fillN, int* __restrict__ fillH,
    int* __restrict__ pinsN, int* __restrict__ pinsH) {
  int e = blockIdx.x * 256 + threadIdx.x;
  if (e < N_PINS) {
    int n = node_idx[e], h = hedge_idx[e];
    int pH = startH[h] + atomicAdd(&fillH[h], 1);
    pinsH[pH] = n;
    int pN = startN[n] + atomicAdd(&fillN[n], 1);
    pinsN[pN] = h;
  }
}

// ---------------------------------------------------------------------------
// transform (MFMA): Vxb[n][128] = bf16(x·Vv), lg[n][4] = x·qv.
// 64 rows/block, 4 waves x 16-row tiles, 9 column tiles (8 Vv + 1 logits).
// ---------------------------------------------------------------------------
__global__ __launch_bounds__(256) void transform_k(
    const ushort_t* __restrict__ xb, const ushort_t* __restrict__ Bsw,
    ushort_t* __restrict__ Vxb, float* __restrict__ lg, int n) {
  __shared__ char Blds[36864];
  __shared__ char Olds[16384];
  int t = threadIdx.x, l = t & 63, w = t >> 6;
  size_t r0 = (size_t)blockIdx.x * 64;
#pragma unroll
  for (int it = 0; it < 9; ++it) {
    int off = it * 4096 + w * 1024 + l * 16;
    gload16((const char*)Bsw + off, Blds + off);
  }
  __syncthreads();

  f32x4 acc[9];
#pragma unroll
  for (int ct = 0; ct < 9; ++ct) acc[ct] = (f32x4){0.f, 0.f, 0.f, 0.f};
  int swz = (l & 7) << 4;
  int lbase = (l & 15) * 256 + (l >> 4) * 16;
  const ushort_t* abase = xb + (r0 + w * 16 + (l & 15)) * 128 + (l >> 4) * 8;
#pragma unroll
  for (int kk = 0; kk < 4; ++kk) {
    bf16x8 a = *(const bf16x8*)(abase + kk * 32);
#pragma unroll
    for (int ct = 0; ct < 9; ++ct) {
      bf16x8 b = *(const bf16x8*)(Blds + ((ct * 4096 + kk * 64 + lbase) ^ swz));
      acc[ct] = __builtin_amdgcn_mfma_f32_16x16x32_bf16(a, b, acc[ct], 0, 0, 0);
    }
  }
  // logits (column tile 8, cols 0..3 valid)
  if ((l & 15) < 4) {
    size_t rb = r0 + w * 16 + (l >> 4) * 4;
#pragma unroll
    for (int j = 0; j < 4; ++j) lg[(rb + j) * 4 + (l & 15)] = acc[8][j];
  }
  // Vx tile -> LDS (swizzled) -> coalesced global bf16
  int row64 = w * 16 + (l >> 4) * 4;
#pragma unroll
  for (int ct = 0; ct < 8; ++ct) {
    int c2 = (ct * 16 + (l & 15)) * 2;
#pragma unroll
    for (int j = 0; j < 4; ++j) {
      int r = row64 + j;
      int addr = (r * 256 + c2) ^ ((r & 0xC) << 3);
      *(ushort_t*)(Olds + addr) = f2bf(acc[ct][j]);
    }
  }
  __syncthreads();
#pragma unroll
  for (int it = 0; it < 4; ++it) {
    int L = it * 4096 + t * 16;
    int r = L >> 8;
    int phys = L ^ ((r & 0xC) << 3);
    *(uint4*)((char*)Vxb + r0 * 256 + L) = *(const uint4*)(Olds + phys);
  }
}

// ---------------------------------------------------------------------------
// attention: wave per target, two-pass segment softmax over bf16 Vx,
// Q-skip + LN0, bf16 xmid out.
// ---------------------------------------------------------------------------
__global__ __launch_bounds__(256) void attn_k(
    const ushort_t* __restrict__ Vxb, const float* __restrict__ lg,
    const int* __restrict__ start, const int* __restrict__ cnt,
    const int* __restrict__ pins, const float* __restrict__ Qflat,
    const float* __restrict__ g0, const float* __restrict__ be0,
    ushort_t* __restrict__ xmidb, int n_tgt) {
  int wid = threadIdx.x >> 6, lane = threadIdx.x & 63;
  int tg = blockIdx.x * 4 + wid;
  if (tg >= n_tgt) return;
  int base = start[tg], deg = cnt[tg];
  int h = lane & 3;
  float m = -3.4e38f;
  for (int i = lane >> 2; i < deg; i += 16) {
    int s = pins[base + i];
    m = fmaxf(m, lg[(size_t)s * 4 + h]);
  }
  m = fmaxf(m, __shfl_xor(m, 4));
  m = fmaxf(m, __shfl_xor(m, 8));
  m = fmaxf(m, __shfl_xor(m, 16));
  m = fmaxf(m, __shfl_xor(m, 32));
  float den = 0.f;
  for (int i = lane >> 2; i < deg; i += 16) {
    int s = pins[base + i];
    den += __expf(lg[(size_t)s * 4 + h] - m);
  }
  den += __shfl_xor(den, 4);
  den += __shfl_xor(den, 8);
  den += __shfl_xor(den, 16);
  den += __shfl_xor(den, 32);
  int h0 = lane >> 5;
  float m0 = __shfl(m, h0), m1 = __shfl(m, h0 + 2);
  float d0 = __shfl(den, h0), d1 = __shfl(den, h0 + 2);
  float rd0 = (deg > 0) ? 1.f / d0 : 0.f;
  float rd1 = (deg > 0) ? 1.f / d1 : 0.f;
  float acc0 = 0.f, acc1 = 0.f;
  for (int e = 0; e < deg; ++e) {
    int s = pins[base + e];
    const ushort_t* vrow = Vxb + (size_t)s * 128;
    float w0 = __expf(lg[(size_t)s * 4 + h0] - m0) * rd0;
    float w1 = __expf(lg[(size_t)s * 4 + h0 + 2] - m1) * rd1;
    acc0 += w0 * bf2f(vrow[lane]);
    acc1 += w1 * bf2f(vrow[lane + 64]);
  }
  float x0v = acc0 + Qflat[lane];
  float x1v = acc1 + Qflat[lane + 64];
  float s1 = x0v + x1v, s2 = x0v * x0v + x1v * x1v;
#pragma unroll
  for (int off = 1; off < 64; off <<= 1) {
    s1 += __shfl_xor(s1, off);
    s2 += __shfl_xor(s2, off);
  }
  float mean = s1 * (1.f / 128.f);
  float var = s2 * (1.f / 128.f) - mean * mean;
  float rs = rsqrtf(var + 1e-5f);
  ushort_t* o = xmidb + (size_t)tg * 128;
  o[lane] = f2bf((x0v - mean) * rs * g0[lane] + be0[lane]);
  o[lane + 64] = f2bf((x1v - mean) * rs * g0[lane + 64] + be0[lane + 64]);
}

// ---------------------------------------------------------------------------
// mlp (MFMA): h=relu(x@W1+b1)@W2+b2; out=relu(LN1(x+h)). 64 rows/block.
// ---------------------------------------------------------------------------
__global__ __launch_bounds__(256) void mlp_k(
    const ushort_t* __restrict__ xmb, const ushort_t* __restrict__ W1sw,
    const float* __restrict__ b1, const ushort_t* __restrict__ W2sw,
    const float* __restrict__ b2, const float* __restrict__ g1,
    const float* __restrict__ be1, float* __restrict__ outf,
    ushort_t* __restrict__ outb, int n, int wf32) {
  __shared__ char Wlds[32768];
  __shared__ char Hlds[16384];
  int t = threadIdx.x, l = t & 63, w = t >> 6;
  size_t r0 = (size_t)blockIdx.x * 64;
#pragma unroll
  for (int it = 0; it < 8; ++it) {
    int off = it * 4096 + w * 1024 + l * 16;
    gload16((const char*)W1sw + off, Wlds + off);
  }
  float b1v[8], b2v[8], g1v[8], be1v[8];
#pragma unroll
  for (int ct = 0; ct < 8; ++ct) {
    int c = ct * 16 + (l & 15);
    b1v[ct] = b1[c]; b2v[ct] = b2[c]; g1v[ct] = g1[c]; be1v[ct] = be1[c];
  }
  __syncthreads();

  int swz = (l & 7) << 4;
  int lbase = (l & 15) * 256 + (l >> 4) * 16;
  f32x4 acc[8];
#pragma unroll
  for (int ct = 0; ct < 8; ++ct) acc[ct] = (f32x4){b1v[ct], b1v[ct], b1v[ct], b1v[ct]};
  const ushort_t* abase = xmb + (r0 + w * 16 + (l & 15)) * 128 + (l >> 4) * 8;
#pragma unroll
  for (int kk = 0; kk < 4; ++kk) {
    bf16x8 a = *(const bf16x8*)(abase + kk * 32);
#pragma unroll
    for (int ct = 0; ct < 8; ++ct) {
      bf16x8 b = *(const bf16x8*)(Wlds + ((ct * 4096 + kk * 64 + lbase) ^ swz));
      acc[ct] = __builtin_amdgcn_mfma_f32_16x16x32_bf16(a, b, acc[ct], 0, 0, 0);
    }
  }
  // h1 -> LDS (per-wave 4KB tile, swizzled for A-frag reads)
  int hbase = w * 4096;
#pragma unroll
  for (int ct = 0; ct < 8; ++ct) {
    int c2 = (ct * 16 + (l & 15)) * 2;
#pragma unroll
    for (int j = 0; j < 4; ++j) {
      int rl = (l >> 4) * 4 + j;
      int addr = hbase + ((rl * 256 + c2) ^ ((rl & 7) << 4));
      *(ushort_t*)(Hlds + addr) = f2bf(fmaxf(acc[ct][j], 0.f));
    }
  }
  __syncthreads();  // all W1 reads + h1 writes complete
#pragma unroll
  for (int it = 0; it < 8; ++it) {
    int off = it * 4096 + w * 1024 + l * 16;
    gload16((const char*)W2sw + off, Wlds + off);
  }
  __syncthreads();  // W2 staged

  f32x4 acc2[8];
#pragma unroll
  for (int ct = 0; ct < 8; ++ct) acc2[ct] = (f32x4){b2v[ct], b2v[ct], b2v[ct], b2v[ct]};
#pragma unroll
  for (int kk = 0; kk < 4; ++kk) {
    bf16x8 a = *(const bf16x8*)(Hlds + (hbase + ((lbase + kk * 64) ^ swz)));
#pragma unroll
    for (int ct = 0; ct < 8; ++ct) {
      bf16x8 b = *(const bf16x8*)(Wlds + ((ct * 4096 + kk * 64 + lbase) ^ swz));
      acc2[ct] = __builtin_amdgcn_mfma_f32_16x16x32_bf16(a, b, acc2[ct], 0, 0, 0);
    }
  }
  // residual + LN1 + relu, in-register (rows = (l>>4)*4+j, cols = ct*16+(l&15))
  size_t rbase = r0 + w * 16 + (l >> 4) * 4;
  float s1[4] = {0.f, 0.f, 0.f, 0.f}, s2[4] = {0.f, 0.f, 0.f, 0.f};
#pragma unroll
  for (int ct = 0; ct < 8; ++ct) {
    int c = ct * 16 + (l & 15);
#pragma unroll
    for (int j = 0; j < 4; ++j) {
      float x = bf2f(xmb[(rbase + j) * 128 + c]);
      float y = acc2[ct][j] + x;
      acc2[ct][j] = y;
      s1[j] += y;
      s2[j] += y * y;
    }
  }
#pragma unroll
  for (int off = 1; off < 16; off <<= 1) {
#pragma unroll
    for (int j = 0; j < 4; ++j) {
      s1[j] += __shfl_xor(s1[j], off);
      s2[j] += __shfl_xor(s2[j], off);
    }
  }
  float mean[4], rs[4];
#pragma unroll
  for (int j = 0; j < 4; ++j) {
    mean[j] = s1[j] * (1.f / 128.f);
    float var = s2[j] * (1.f / 128.f) - mean[j] * mean[j];
    rs[j] = rsqrtf(var + 1e-5f);
  }
#pragma unroll
  for (int ct = 0; ct < 8; ++ct) {
    int c = ct * 16 + (l & 15);
#pragma unroll
    for (int j = 0; j < 4; ++j) {
      float o = fmaxf((acc2[ct][j] - mean[j]) * rs[j] * g1v[ct] + be1v[ct], 0.f);
      size_t row = rbase + j;
      outb[row * 128 + c] = f2bf(o);
      if (wf32 && row < (size_t)n) outf[row * 128 + c] = o;
    }
  }
}

// ---------------------------------------------------------------------------
extern "C" void kernel_launch(void* const* d_in, const int* in_sizes, int n_in,
                              void* d_out, int out_size, void* d_ws, size_t ws_size,
                              hipStream_t stream) {
  const float* x0_in = (const float*)d_in[0];
  const float* Kw  = (const float*)d_in[1];
  const float* Vw  = (const float*)d_in[2];
  const float* Qw  = (const float*)d_in[3];
  const float* W1  = (const float*)d_in[4];
  const float* b1  = (const float*)d_in[5];
  const float* W2  = (const float*)d_in[6];
  const float* b2  = (const float*)d_in[7];
  const float* ln0g = (const float*)d_in[8];
  const float* ln0b = (const float*)d_in[9];
  const float* ln1g = (const float*)d_in[10];
  const float* ln1b = (const float*)d_in[11];
  const int* node_idx  = (const int*)d_in[12];
  const int* hedge_idx = (const int*)d_in[13];

  float* out = (float*)d_out;
  float* x0_out = out;
  float* x1_out = out + (size_t)N_NODES * 128;

  char* w = (char*)d_ws;
  auto alloc = [&](size_t bytes) -> void* {
    void* p = (void*)w;
    w += (bytes + 255) & ~(size_t)255;
    return p;
  };
  ushort_t* Vvqsw = (ushort_t*)alloc(4 * 18432 * 2);
  ushort_t* W1sw  = (ushort_t*)alloc(4 * 16384 * 2);
  ushort_t* W2sw  = (ushort_t*)alloc(4 * 16384 * 2);
  ushort_t* x0b   = (ushort_t*)alloc((size_t)NPN * 128 * 2);
  ushort_t* x1b   = (ushort_t*)alloc((size_t)NPH * 128 * 2);
  ushort_t* Vxb   = (ushort_t*)alloc((size_t)NPN * 128 * 2);
  float*    lg    = (float*)alloc((size_t)NPN * 4 * 4);
  ushort_t* xmidb = (ushort_t*)alloc((size_t)NPN * 128 * 2);
  int* startH = (int*)alloc(N_HEDGES * 4);
  int* startN = (int*)alloc(N_NODES * 4);
  int* pinsH  = (int*)alloc(N_PINS * 4);
  int* pinsN  = (int*)alloc(N_PINS * 4);
  int* zbase  = (int*)alloc((size_t)(2 * (N_HEDGES + N_NODES) + 2) * 4);
  int* cntH = zbase;
  int* cntN = cntH + N_HEDGES;
  int* fillH = cntN + N_NODES;
  int* fillN = fillH + N_HEDGES;
  int* gctr = fillN + N_NODES;

  hipMemsetAsync(zbase, 0, (size_t)(2 * (N_HEDGES + N_NODES) + 2) * 4, stream);

  conv_k<<<(N_NODES * 128 / 4 + 255) / 256, 256, 0, stream>>>(x0_in, x0b, N_NODES * 32);
  prep_k<<<288, 256, 0, stream>>>(Kw, Vw, Qw, W1, W2, Vvqsw, W1sw, W2sw);
  csr_count<<<(N_PINS + 255) / 256, 256, 0, stream>>>(node_idx, hedge_idx, cntN, cntH);
  csr_scan<<<(N_HEDGES + 255) / 256, 256, 0, stream>>>(cntH, startH, N_HEDGES, gctr + 0);
  csr_scan<<<(N_NODES + 255) / 256, 256, 0, stream>>>(cntN, startN, N_NODES, gctr + 1);
  csr_fill<<<(N_PINS + 255) / 256, 256, 0, stream>>>(node_idx, hedge_idx, startN, startH,
                                                     fillN, fillH, pinsN, pinsH);

  const ushort_t* srcs[4] = {x0b, x1b, x0b, x1b};
  int n_srcs[4] = {N_NODES, N_HEDGES, N_NODES, N_HEDGES};
  const int* starts[4] = {startH, startN, startH, startN};
  const int* cnts[4] = {cntH, cntN, cntH, cntN};
  const int* pinss[4] = {pinsH, pinsN, pinsH, pinsN};
  int n_tgts[4] = {N_HEDGES, N_NODES, N_HEDGES, N_NODES};
  float* outf[4] = {x1_out, x0_out, x1_out, x0_out};
  ushort_t* outbs[4] = {x1b, x0b, x1b, x0b};
  int wf32[4] = {0, 0, 1, 1};

  for (int b = 0; b < 4; ++b) {
    int n_src = n_srcs[b], n_tgt = n_tgts[b];
    transform_k<<<(n_src + 63) / 64, 256, 0, stream>>>(srcs[b], Vvqsw + b * 18432,
                                                       Vxb, lg, n_src);
    attn_k<<<(n_tgt + 3) / 4, 256, 0, stream>>>(Vxb, lg, starts[b], cnts[b], pinss[b],
                                                Qw + b * 128, ln0g + b * 128,
                                                ln0b + b * 128, xmidb, n_tgt);
    mlp_k<<<(n_tgt + 63) / 64, 256, 0, stream>>>(xmidb, W1sw + b * 16384, b1 + b * 128,
                                                 W2sw + b * 16384, b2 + b * 128,
                                                 ln1g + b * 128, ln1b + b * 128,
                                                 outf[b], outbs[b], n_tgt, wf32[b]);
  }
}

// Round 3
// 410.625 us; speedup vs baseline: 2.5589x; 1.1599x over previous
//
#include <hip/hip_runtime.h>

#define N_NODES 100000
#define N_HEDGES 30000
#define N_PINS 400000
#define NPN 100096   // padded node rows (>= 1563*64)
#define NPH 30080    // padded hedge rows (>= 469*64)

typedef __attribute__((ext_vector_type(8))) short bf16x8;
typedef __attribute__((ext_vector_type(4))) float f32x4;
typedef unsigned short ushort_t;

__device__ __forceinline__ unsigned short f2bf(float f) {
  unsigned int u = __float_as_uint(f);
  u += 0x7FFF + ((u >> 16) & 1);
  return (unsigned short)(u >> 16);
}
__device__ __forceinline__ float bf2f(unsigned short s) {
  return __uint_as_float(((unsigned int)s) << 16);
}
__device__ __forceinline__ void gload16(const void* g, void* l) {
  __builtin_amdgcn_global_load_lds(
      (const __attribute__((address_space(1))) unsigned int*)g,
      (__attribute__((address_space(3))) unsigned int*)l, 16, 0, 0);
}

// ---------------------------------------------------------------------------
// prep: build bf16, transposed, XOR-swizzled B-matrices (as round 2).
// ---------------------------------------------------------------------------
__global__ __launch_bounds__(256) void prep_k(
    const float* __restrict__ Kw, const float* __restrict__ Vw,
    const float* __restrict__ Qw, const float* __restrict__ W1,
    const float* __restrict__ W2, ushort_t* __restrict__ Vvqsw,
    ushort_t* __restrict__ W1sw, ushort_t* __restrict__ W2sw) {
  int i = blockIdx.x * 256 + threadIdx.x;
  if (i < 4 * 144 * 128) {
    int b = i / 18432, r = i % 18432, c = r >> 7, d = r & 127;
    float v;
    if (c < 128) {
      v = Vw[((b * 4 + (c >> 5)) * 128 + d) * 32 + (c & 31)];
    } else if (c < 132) {
      int h = c - 128;
      const float* kp = Kw + ((b * 4 + h) * 128 + d) * 32;
      const float* qp = Qw + (b * 4 + h) * 32;
      float s = 0.f;
      for (int k = 0; k < 32; ++k) s += kp[k] * qp[k];
      v = s;
    } else {
      v = 0.f;
    }
    int L = (c * 256 + d * 2) ^ ((c & 7) << 4);
    Vvqsw[b * 18432 + L / 2] = f2bf(v);
  }
  if (i < 4 * 128 * 128) {
    int b = i >> 14, r = i & 16383, c = r >> 7, k = r & 127;
    int L = (c * 256 + k * 2) ^ ((c & 7) << 4);
    int idx = b * 16384 + L / 2;
    W1sw[idx] = f2bf(W1[b * 16384 + k * 128 + c]);
    W2sw[idx] = f2bf(W2[b * 16384 + k * 128 + c]);
  }
}

__global__ __launch_bounds__(256) void conv_k(const float* __restrict__ x,
                                              ushort_t* __restrict__ xb, int n4) {
  int i = blockIdx.x * 256 + threadIdx.x;
  if (i < n4) {
    float4 v = ((const float4*)x)[i];
    ushort_t o0 = f2bf(v.x), o1 = f2bf(v.y), o2 = f2bf(v.z), o3 = f2bf(v.w);
    ushort_t* p = xb + (size_t)i * 4;
    p[0] = o0; p[1] = o1; p[2] = o2; p[3] = o3;
  }
}

// ---------------------------------------------------------------------------
// CSR build
// ---------------------------------------------------------------------------
__global__ __launch_bounds__(256) void csr_count(
    const int* __restrict__ node_idx, const int* __restrict__ hedge_idx,
    int* __restrict__ cntN, int* __restrict__ cntH) {
  int e = blockIdx.x * 256 + threadIdx.x;
  if (e < N_PINS) {
    atomicAdd(&cntN[node_idx[e]], 1);
    atomicAdd(&cntH[hedge_idx[e]], 1);
  }
}

__global__ __launch_bounds__(256) void csr_scan(
    const int* __restrict__ cnt, int* __restrict__ start, int2* __restrict__ seg,
    int n, int* gctr) {
  __shared__ int wsum[4];
  __shared__ int bbase;
  int i = blockIdx.x * 256 + threadIdx.x;
  int lane = threadIdx.x & 63, wid = threadIdx.x >> 6;
  int v = (i < n) ? cnt[i] : 0;
  int sc = v;
#pragma unroll
  for (int s = 1; s < 64; s <<= 1) {
    int tv = __shfl_up(sc, s);
    if (lane >= s) sc += tv;
  }
  if (lane == 63) wsum[wid] = sc;
  __syncthreads();
  if (threadIdx.x == 0) {
    int s0 = wsum[0], s1 = wsum[1], s2 = wsum[2], s3 = wsum[3];
    wsum[0] = 0; wsum[1] = s0; wsum[2] = s0 + s1; wsum[3] = s0 + s1 + s2;
    bbase = atomicAdd(gctr, s0 + s1 + s2 + s3);
  }
  __syncthreads();
  if (i < n) {
    int st = bbase + wsum[wid] + (sc - v);
    start[i] = st;
    seg[i] = make_int2(st, v);
  }
}

__global__ __launch_bounds__(256) void csr_fill(
    const int* __restrict__ node_idx, const int* __restrict__ hedge_idx,
    const int* __restrict__ startN, const int* __restrict__ startH,
    int* __restrict__ fillN, int* __restrict__ fillH,
    int* __restrict__ pinsN, int* __restrict__ pinsH) {
  int e = blockIdx.x * 256 + threadIdx.x;
  if (e < N_PINS) {
    int n = node_idx[e], h = hedge_idx[e];
    int pH = startH[h] + atomicAdd(&fillH[h], 1);
    pinsH[pH] = n;
    int pN = startN[n] + atomicAdd(&fillN[n], 1);
    pinsN[pN] = h;
  }
}

// ---------------------------------------------------------------------------
// transform (MFMA), as round 2
// ---------------------------------------------------------------------------
__global__ __launch_bounds__(256) void transform_k(
    const ushort_t* __restrict__ xb, const ushort_t* __restrict__ Bsw,
    ushort_t* __restrict__ Vxb, float* __restrict__ lg, int n) {
  __shared__ char Blds[36864];
  __shared__ char Olds[16384];
  int t = threadIdx.x, l = t & 63, w = t >> 6;
  size_t r0 = (size_t)blockIdx.x * 64;
#pragma unroll
  for (int it = 0; it < 9; ++it) {
    int off = it * 4096 + w * 1024 + l * 16;
    gload16((const char*)Bsw + off, Blds + off);
  }
  __syncthreads();

  f32x4 acc[9];
#pragma unroll
  for (int ct = 0; ct < 9; ++ct) acc[ct] = (f32x4){0.f, 0.f, 0.f, 0.f};
  int swz = (l & 7) << 4;
  int lbase = (l & 15) * 256 + (l >> 4) * 16;
  const ushort_t* abase = xb + (r0 + w * 16 + (l & 15)) * 128 + (l >> 4) * 8;
#pragma unroll
  for (int kk = 0; kk < 4; ++kk) {
    bf16x8 a = *(const bf16x8*)(abase + kk * 32);
#pragma unroll
    for (int ct = 0; ct < 9; ++ct) {
      bf16x8 b = *(const bf16x8*)(Blds + ((ct * 4096 + kk * 64 + lbase) ^ swz));
      acc[ct] = __builtin_amdgcn_mfma_f32_16x16x32_bf16(a, b, acc[ct], 0, 0, 0);
    }
  }
  if ((l & 15) < 4) {
    size_t rb = r0 + w * 16 + (l >> 4) * 4;
#pragma unroll
    for (int j = 0; j < 4; ++j) lg[(rb + j) * 4 + (l & 15)] = acc[8][j];
  }
  int row64 = w * 16 + (l >> 4) * 4;
#pragma unroll
  for (int ct = 0; ct < 8; ++ct) {
    int c2 = (ct * 16 + (l & 15)) * 2;
#pragma unroll
    for (int j = 0; j < 4; ++j) {
      int r = row64 + j;
      int addr = (r * 256 + c2) ^ ((r & 0xC) << 3);
      *(ushort_t*)(Olds + addr) = f2bf(acc[ct][j]);
    }
  }
  __syncthreads();
#pragma unroll
  for (int it = 0; it < 4; ++it) {
    int L = it * 4096 + t * 16;
    int r = L >> 8;
    int phys = L ^ ((r & 0xC) << 3);
    *(uint4*)((char*)Vxb + r0 * 256 + L) = *(const uint4*)(Olds + phys);
  }
}

// ---------------------------------------------------------------------------
// attention v2: wave per target. One-shot softmax (deg<=64 fast path): lane
// e owns pin e, loads its float4 logits once; butterfly max/sum; normalized
// per-head weights + pin byte-offsets staged in per-wave LDS. Gather loop:
// 2 cols/lane (uint = 2 bf16), unrolled x4. Fused Q-skip + LN0.
// ---------------------------------------------------------------------------
__global__ __launch_bounds__(256) void attn_k(
    const ushort_t* __restrict__ Vxb, const float* __restrict__ lg,
    const int2* __restrict__ seg, const int* __restrict__ pins,
    const float* __restrict__ Qflat, const float* __restrict__ g0,
    const float* __restrict__ be0, ushort_t* __restrict__ xmidb, int n_tgt) {
  __shared__ float wlds[4][64][4];
  __shared__ int plds[4][64];
  int wid = threadIdx.x >> 6, lane = threadIdx.x & 63;
  int tg = blockIdx.x * 4 + wid;
  if (tg >= n_tgt) return;
  int2 sc = seg[tg];
  int base = sc.x, deg = sc.y;
  int head = lane >> 4;  // cols 2*lane, 2*lane+1 -> head = (2*lane)>>5
  float acc0 = 0.f, acc1 = 0.f;
  const char* vb = (const char*)Vxb;

  if (deg > 0 && deg <= 64) {
    bool act = lane < deg;
    int p = act ? pins[base + lane] : 0;
    float4 l4;
    if (act) l4 = *(const float4*)(lg + p * 4);
    else l4 = make_float4(-3.4e38f, -3.4e38f, -3.4e38f, -3.4e38f);
    float m0 = l4.x, m1 = l4.y, m2 = l4.z, m3 = l4.w;
#pragma unroll
    for (int off = 1; off < 64; off <<= 1) {
      m0 = fmaxf(m0, __shfl_xor(m0, off));
      m1 = fmaxf(m1, __shfl_xor(m1, off));
      m2 = fmaxf(m2, __shfl_xor(m2, off));
      m3 = fmaxf(m3, __shfl_xor(m3, off));
    }
    float e0 = __expf(l4.x - m0), e1 = __expf(l4.y - m1);
    float e2 = __expf(l4.z - m2), e3 = __expf(l4.w - m3);
    float s0 = e0, s1 = e1, s2 = e2, s3 = e3;
#pragma unroll
    for (int off = 1; off < 64; off <<= 1) {
      s0 += __shfl_xor(s0, off);
      s1 += __shfl_xor(s1, off);
      s2 += __shfl_xor(s2, off);
      s3 += __shfl_xor(s3, off);
    }
    wlds[wid][lane][0] = e0 / s0;
    wlds[wid][lane][1] = e1 / s1;
    wlds[wid][lane][2] = e2 / s2;
    wlds[wid][lane][3] = e3 / s3;
    plds[wid][lane] = p << 8;  // row byte offset (128 ushorts = 256B)
    int e = 0;
    for (; e + 4 <= deg; e += 4) {
      int o0 = plds[wid][e], o1 = plds[wid][e + 1];
      int o2 = plds[wid][e + 2], o3 = plds[wid][e + 3];
      float w0 = wlds[wid][e][head], w1 = wlds[wid][e + 1][head];
      float w2 = wlds[wid][e + 2][head], w3 = wlds[wid][e + 3][head];
      unsigned int v0 = *(const unsigned int*)(vb + o0 + lane * 4);
      unsigned int v1 = *(const unsigned int*)(vb + o1 + lane * 4);
      unsigned int v2 = *(const unsigned int*)(vb + o2 + lane * 4);
      unsigned int v3 = *(const unsigned int*)(vb + o3 + lane * 4);
      acc0 = fmaf(w0, __uint_as_float(v0 << 16), acc0);
      acc1 = fmaf(w0, __uint_as_float(v0 & 0xffff0000u), acc1);
      acc0 = fmaf(w1, __uint_as_float(v1 << 16), acc0);
      acc1 = fmaf(w1, __uint_as_float(v1 & 0xffff0000u), acc1);
      acc0 = fmaf(w2, __uint_as_float(v2 << 16), acc0);
      acc1 = fmaf(w2, __uint_as_float(v2 & 0xffff0000u), acc1);
      acc0 = fmaf(w3, __uint_as_float(v3 << 16), acc0);
      acc1 = fmaf(w3, __uint_as_float(v3 & 0xffff0000u), acc1);
    }
    for (; e < deg; ++e) {
      int o = plds[wid][e];
      float w0 = wlds[wid][e][head];
      unsigned int v = *(const unsigned int*)(vb + o + lane * 4);
      acc0 = fmaf(w0, __uint_as_float(v << 16), acc0);
      acc1 = fmaf(w0, __uint_as_float(v & 0xffff0000u), acc1);
    }
  } else if (deg > 64) {
    float m0 = -3.4e38f, m1 = -3.4e38f, m2 = -3.4e38f, m3 = -3.4e38f;
    for (int i = lane; i < deg; i += 64) {
      int p = pins[base + i];
      float4 l4 = *(const float4*)(lg + p * 4);
      m0 = fmaxf(m0, l4.x); m1 = fmaxf(m1, l4.y);
      m2 = fmaxf(m2, l4.z); m3 = fmaxf(m3, l4.w);
    }
#pragma unroll
    for (int off = 1; off < 64; off <<= 1) {
      m0 = fmaxf(m0, __shfl_xor(m0, off));
      m1 = fmaxf(m1, __shfl_xor(m1, off));
      m2 = fmaxf(m2, __shfl_xor(m2, off));
      m3 = fmaxf(m3, __shfl_xor(m3, off));
    }
    float s0 = 0.f, s1 = 0.f, s2 = 0.f, s3 = 0.f;
    for (int i = lane; i < deg; i += 64) {
      int p = pins[base + i];
      float4 l4 = *(const float4*)(lg + p * 4);
      s0 += __expf(l4.x - m0); s1 += __expf(l4.y - m1);
      s2 += __expf(l4.z - m2); s3 += __expf(l4.w - m3);
    }
#pragma unroll
    for (int off = 1; off < 64; off <<= 1) {
      s0 += __shfl_xor(s0, off);
      s1 += __shfl_xor(s1, off);
      s2 += __shfl_xor(s2, off);
      s3 += __shfl_xor(s3, off);
    }
    float mh = (head & 2) ? ((head & 1) ? m3 : m2) : ((head & 1) ? m1 : m0);
    float sh = (head & 2) ? ((head & 1) ? s3 : s2) : ((head & 1) ? s1 : s0);
    float rdh = 1.f / sh;
    for (int e = 0; e < deg; ++e) {
      int p = pins[base + e];
      float w0 = __expf(lg[p * 4 + head] - mh) * rdh;
      unsigned int v = *(const unsigned int*)(vb + (p << 8) + lane * 4);
      acc0 = fmaf(w0, __uint_as_float(v << 16), acc0);
      acc1 = fmaf(w0, __uint_as_float(v & 0xffff0000u), acc1);
    }
  }

  float2 q2 = ((const float2*)Qflat)[lane];
  float x0v = acc0 + q2.x;
  float x1v = acc1 + q2.y;
  float s1v = x0v + x1v, s2v = x0v * x0v + x1v * x1v;
#pragma unroll
  for (int off = 1; off < 64; off <<= 1) {
    s1v += __shfl_xor(s1v, off);
    s2v += __shfl_xor(s2v, off);
  }
  float mean = s1v * (1.f / 128.f);
  float var = s2v * (1.f / 128.f) - mean * mean;
  float rs = rsqrtf(var + 1e-5f);
  float2 gg = ((const float2*)g0)[lane];
  float2 bb = ((const float2*)be0)[lane];
  float o0 = (x0v - mean) * rs * gg.x + bb.x;
  float o1 = (x1v - mean) * rs * gg.y + bb.y;
  unsigned int pk = ((unsigned int)f2bf(o1) << 16) | f2bf(o0);
  ((unsigned int*)xmidb)[tg * 64 + lane] = pk;
}

// ---------------------------------------------------------------------------
// mlp (MFMA), as round 2
// ---------------------------------------------------------------------------
__global__ __launch_bounds__(256) void mlp_k(
    const ushort_t* __restrict__ xmb, const ushort_t* __restrict__ W1sw,
    const float* __restrict__ b1, const ushort_t* __restrict__ W2sw,
    const float* __restrict__ b2, const float* __restrict__ g1,
    const float* __restrict__ be1, float* __restrict__ outf,
    ushort_t* __restrict__ outb, int n, int wf32) {
  __shared__ char Wlds[32768];
  __shared__ char Hlds[16384];
  int t = threadIdx.x, l = t & 63, w = t >> 6;
  size_t r0 = (size_t)blockIdx.x * 64;
#pragma unroll
  for (int it = 0; it < 8; ++it) {
    int off = it * 4096 + w * 1024 + l * 16;
    gload16((const char*)W1sw + off, Wlds + off);
  }
  float b1v[8], b2v[8], g1v[8], be1v[8];
#pragma unroll
  for (int ct = 0; ct < 8; ++ct) {
    int c = ct * 16 + (l & 15);
    b1v[ct] = b1[c]; b2v[ct] = b2[c]; g1v[ct] = g1[c]; be1v[ct] = be1[c];
  }
  __syncthreads();

  int swz = (l & 7) << 4;
  int lbase = (l & 15) * 256 + (l >> 4) * 16;
  f32x4 acc[8];
#pragma unroll
  for (int ct = 0; ct < 8; ++ct) acc[ct] = (f32x4){b1v[ct], b1v[ct], b1v[ct], b1v[ct]};
  const ushort_t* abase = xmb + (r0 + w * 16 + (l & 15)) * 128 + (l >> 4) * 8;
#pragma unroll
  for (int kk = 0; kk < 4; ++kk) {
    bf16x8 a = *(const bf16x8*)(abase + kk * 32);
#pragma unroll
    for (int ct = 0; ct < 8; ++ct) {
      bf16x8 b = *(const bf16x8*)(Wlds + ((ct * 4096 + kk * 64 + lbase) ^ swz));
      acc[ct] = __builtin_amdgcn_mfma_f32_16x16x32_bf16(a, b, acc[ct], 0, 0, 0);
    }
  }
  int hbase = w * 4096;
#pragma unroll
  for (int ct = 0; ct < 8; ++ct) {
    int c2 = (ct * 16 + (l & 15)) * 2;
#pragma unroll
    for (int j = 0; j < 4; ++j) {
      int rl = (l >> 4) * 4 + j;
      int addr = hbase + ((rl * 256 + c2) ^ ((rl & 7) << 4));
      *(ushort_t*)(Hlds + addr) = f2bf(fmaxf(acc[ct][j], 0.f));
    }
  }
  __syncthreads();
#pragma unroll
  for (int it = 0; it < 8; ++it) {
    int off = it * 4096 + w * 1024 + l * 16;
    gload16((const char*)W2sw + off, Wlds + off);
  }
  __syncthreads();

  f32x4 acc2[8];
#pragma unroll
  for (int ct = 0; ct < 8; ++ct) acc2[ct] = (f32x4){b2v[ct], b2v[ct], b2v[ct], b2v[ct]};
#pragma unroll
  for (int kk = 0; kk < 4; ++kk) {
    bf16x8 a = *(const bf16x8*)(Hlds + (hbase + ((lbase + kk * 64) ^ swz)));
#pragma unroll
    for (int ct = 0; ct < 8; ++ct) {
      bf16x8 b = *(const bf16x8*)(Wlds + ((ct * 4096 + kk * 64 + lbase) ^ swz));
      acc2[ct] = __builtin_amdgcn_mfma_f32_16x16x32_bf16(a, b, acc2[ct], 0, 0, 0);
    }
  }
  size_t rbase = r0 + w * 16 + (l >> 4) * 4;
  float s1[4] = {0.f, 0.f, 0.f, 0.f}, s2[4] = {0.f, 0.f, 0.f, 0.f};
#pragma unroll
  for (int ct = 0; ct < 8; ++ct) {
    int c = ct * 16 + (l & 15);
#pragma unroll
    for (int j = 0; j < 4; ++j) {
      float x = bf2f(xmb[(rbase + j) * 128 + c]);
      float y = acc2[ct][j] + x;
      acc2[ct][j] = y;
      s1[j] += y;
      s2[j] += y * y;
    }
  }
#pragma unroll
  for (int off = 1; off < 16; off <<= 1) {
#pragma unroll
    for (int j = 0; j < 4; ++j) {
      s1[j] += __shfl_xor(s1[j], off);
      s2[j] += __shfl_xor(s2[j], off);
    }
  }
  float mean[4], rs[4];
#pragma unroll
  for (int j = 0; j < 4; ++j) {
    mean[j] = s1[j] * (1.f / 128.f);
    float var = s2[j] * (1.f / 128.f) - mean[j] * mean[j];
    rs[j] = rsqrtf(var + 1e-5f);
  }
#pragma unroll
  for (int ct = 0; ct < 8; ++ct) {
    int c = ct * 16 + (l & 15);
#pragma unroll
    for (int j = 0; j < 4; ++j) {
      float o = fmaxf((acc2[ct][j] - mean[j]) * rs[j] * g1v[ct] + be1v[ct], 0.f);
      size_t row = rbase + j;
      outb[row * 128 + c] = f2bf(o);
      if (wf32 && row < (size_t)n) outf[row * 128 + c] = o;
    }
  }
}

// ---------------------------------------------------------------------------
extern "C" void kernel_launch(void* const* d_in, const int* in_sizes, int n_in,
                              void* d_out, int out_size, void* d_ws, size_t ws_size,
                              hipStream_t stream) {
  const float* x0_in = (const float*)d_in[0];
  const float* Kw  = (const float*)d_in[1];
  const float* Vw  = (const float*)d_in[2];
  const float* Qw  = (const float*)d_in[3];
  const float* W1  = (const float*)d_in[4];
  const float* b1  = (const float*)d_in[5];
  const float* W2  = (const float*)d_in[6];
  const float* b2  = (const float*)d_in[7];
  const float* ln0g = (const float*)d_in[8];
  const float* ln0b = (const float*)d_in[9];
  const float* ln1g = (const float*)d_in[10];
  const float* ln1b = (const float*)d_in[11];
  const int* node_idx  = (const int*)d_in[12];
  const int* hedge_idx = (const int*)d_in[13];

  float* out = (float*)d_out;
  float* x0_out = out;
  float* x1_out = out + (size_t)N_NODES * 128;

  char* w = (char*)d_ws;
  auto alloc = [&](size_t bytes) -> void* {
    void* p = (void*)w;
    w += (bytes + 255) & ~(size_t)255;
    return p;
  };
  ushort_t* Vvqsw = (ushort_t*)alloc(4 * 18432 * 2);
  ushort_t* W1sw  = (ushort_t*)alloc(4 * 16384 * 2);
  ushort_t* W2sw  = (ushort_t*)alloc(4 * 16384 * 2);
  ushort_t* x0b   = (ushort_t*)alloc((size_t)NPN * 128 * 2);
  ushort_t* x1b   = (ushort_t*)alloc((size_t)NPH * 128 * 2);
  ushort_t* Vxb   = (ushort_t*)alloc((size_t)NPN * 128 * 2);
  float*    lg    = (float*)alloc((size_t)NPN * 4 * 4);
  ushort_t* xmidb = (ushort_t*)alloc((size_t)NPN * 128 * 2);
  int* startH = (int*)alloc(N_HEDGES * 4);
  int* startN = (int*)alloc(N_NODES * 4);
  int2* segH  = (int2*)alloc((size_t)N_HEDGES * 8);
  int2* segN  = (int2*)alloc((size_t)N_NODES * 8);
  int* pinsH  = (int*)alloc(N_PINS * 4);
  int* pinsN  = (int*)alloc(N_PINS * 4);
  int* zbase  = (int*)alloc((size_t)(2 * (N_HEDGES + N_NODES) + 2) * 4);
  int* cntH = zbase;
  int* cntN = cntH + N_HEDGES;
  int* fillH = cntN + N_NODES;
  int* fillN = fillH + N_HEDGES;
  int* gctr = fillN + N_NODES;

  hipMemsetAsync(zbase, 0, (size_t)(2 * (N_HEDGES + N_NODES) + 2) * 4, stream);

  conv_k<<<(N_NODES * 128 / 4 + 255) / 256, 256, 0, stream>>>(x0_in, x0b, N_NODES * 32);
  prep_k<<<288, 256, 0, stream>>>(Kw, Vw, Qw, W1, W2, Vvqsw, W1sw, W2sw);
  csr_count<<<(N_PINS + 255) / 256, 256, 0, stream>>>(node_idx, hedge_idx, cntN, cntH);
  csr_scan<<<(N_HEDGES + 255) / 256, 256, 0, stream>>>(cntH, startH, segH, N_HEDGES, gctr + 0);
  csr_scan<<<(N_NODES + 255) / 256, 256, 0, stream>>>(cntN, startN, segN, N_NODES, gctr + 1);
  csr_fill<<<(N_PINS + 255) / 256, 256, 0, stream>>>(node_idx, hedge_idx, startN, startH,
                                                     fillN, fillH, pinsN, pinsH);

  const ushort_t* srcs[4] = {x0b, x1b, x0b, x1b};
  int n_srcs[4] = {N_NODES, N_HEDGES, N_NODES, N_HEDGES};
  const int2* segs[4] = {segH, segN, segH, segN};
  const int* pinss[4] = {pinsH, pinsN, pinsH, pinsN};
  int n_tgts[4] = {N_HEDGES, N_NODES, N_HEDGES, N_NODES};
  float* outf[4] = {x1_out, x0_out, x1_out, x0_out};
  ushort_t* outbs[4] = {x1b, x0b, x1b, x0b};
  int wf32[4] = {0, 0, 1, 1};

  for (int b = 0; b < 4; ++b) {
    int n_src = n_srcs[b], n_tgt = n_tgts[b];
    transform_k<<<(n_src + 63) / 64, 256, 0, stream>>>(srcs[b], Vvqsw + b * 18432,
                                                       Vxb, lg, n_src);
    attn_k<<<(n_tgt + 3) / 4, 256, 0, stream>>>(Vxb, lg, segs[b], pinss[b],
                                                Qw + b * 128, ln0g + b * 128,
                                                ln0b + b * 128, xmidb, n_tgt);
    mlp_k<<<(n_tgt + 63) / 64, 256, 0, stream>>>(xmidb, W1sw + b * 16384, b1 + b * 128,
                                                 W2sw + b * 16384, b2 + b * 128,
                                                 ln1g + b * 128, ln1b + b * 128,
                                                 outf[b], outbs[b], n_tgt, wf32[b]);
  }
}

// Round 4
// 315.563 us; speedup vs baseline: 3.3298x; 1.3012x over previous
//
#include <hip/hip_runtime.h>

#define N_NODES 100000
#define N_HEDGES 30000
#define N_PINS 400000
#define NPN 100096   // padded node rows (>= 1563*64)
#define NPH 30080    // padded hedge rows (>= 469*64)
#define OVF_CAP 8192

typedef __attribute__((ext_vector_type(8))) short bf16x8;
typedef __attribute__((ext_vector_type(4))) float f32x4;
typedef unsigned short ushort_t;

__device__ __forceinline__ unsigned short f2bf(float f) {
  unsigned int u = __float_as_uint(f);
  u += 0x7FFF + ((u >> 16) & 1);
  return (unsigned short)(u >> 16);
}
__device__ __forceinline__ float bf2f(unsigned short s) {
  return __uint_as_float(((unsigned int)s) << 16);
}
__device__ __forceinline__ void gload16(const void* g, void* l) {
  __builtin_amdgcn_global_load_lds(
      (const __attribute__((address_space(1))) unsigned int*)g,
      (__attribute__((address_space(3))) unsigned int*)l, 16, 0, 0);
}

// ---------------------------------------------------------------------------
// prep: build bf16, transposed, XOR-swizzled B-matrices (as round 2).
// ---------------------------------------------------------------------------
__global__ __launch_bounds__(256) void prep_k(
    const float* __restrict__ Kw, const float* __restrict__ Vw,
    const float* __restrict__ Qw, const float* __restrict__ W1,
    const float* __restrict__ W2, ushort_t* __restrict__ Vvqsw,
    ushort_t* __restrict__ W1sw, ushort_t* __restrict__ W2sw) {
  int i = blockIdx.x * 256 + threadIdx.x;
  if (i < 4 * 144 * 128) {
    int b = i / 18432, r = i % 18432, c = r >> 7, d = r & 127;
    float v;
    if (c < 128) {
      v = Vw[((b * 4 + (c >> 5)) * 128 + d) * 32 + (c & 31)];
    } else if (c < 132) {
      int h = c - 128;
      const float* kp = Kw + ((b * 4 + h) * 128 + d) * 32;
      const float* qp = Qw + (b * 4 + h) * 32;
      float s = 0.f;
      for (int k = 0; k < 32; ++k) s += kp[k] * qp[k];
      v = s;
    } else {
      v = 0.f;
    }
    int L = (c * 256 + d * 2) ^ ((c & 7) << 4);
    Vvqsw[b * 18432 + L / 2] = f2bf(v);
  }
  if (i < 4 * 128 * 128) {
    int b = i >> 14, r = i & 16383, c = r >> 7, k = r & 127;
    int L = (c * 256 + k * 2) ^ ((c & 7) << 4);
    int idx = b * 16384 + L / 2;
    W1sw[idx] = f2bf(W1[b * 16384 + k * 128 + c]);
    W2sw[idx] = f2bf(W2[b * 16384 + k * 128 + c]);
  }
}

__global__ __launch_bounds__(256) void conv_k(const float* __restrict__ x,
                                              ushort_t* __restrict__ xb, int n4) {
  int i = blockIdx.x * 256 + threadIdx.x;
  if (i < n4) {
    float4 v = ((const float4*)x)[i];
    ushort_t o0 = f2bf(v.x), o1 = f2bf(v.y), o2 = f2bf(v.z), o3 = f2bf(v.w);
    ushort_t* p = xb + (size_t)i * 4;
    p[0] = o0; p[1] = o1; p[2] = o2; p[3] = o3;
  }
}

// ---------------------------------------------------------------------------
// CSR build
// ---------------------------------------------------------------------------
__global__ __launch_bounds__(256) void csr_count(
    const int* __restrict__ node_idx, const int* __restrict__ hedge_idx,
    int* __restrict__ cntN, int* __restrict__ cntH) {
  int e = blockIdx.x * 256 + threadIdx.x;
  if (e < N_PINS) {
    atomicAdd(&cntN[node_idx[e]], 1);
    atomicAdd(&cntH[hedge_idx[e]], 1);
  }
}

__global__ __launch_bounds__(256) void csr_scan(
    const int* __restrict__ cnt, int* __restrict__ start, int2* __restrict__ seg,
    int n, int* gctr, int thresh, int* __restrict__ ovf, int* __restrict__ ovfcnt) {
  __shared__ int wsum[4];
  __shared__ int bbase;
  int i = blockIdx.x * 256 + threadIdx.x;
  int lane = threadIdx.x & 63, wid = threadIdx.x >> 6;
  int v = (i < n) ? cnt[i] : 0;
  int sc = v;
#pragma unroll
  for (int s = 1; s < 64; s <<= 1) {
    int tv = __shfl_up(sc, s);
    if (lane >= s) sc += tv;
  }
  if (lane == 63) wsum[wid] = sc;
  __syncthreads();
  if (threadIdx.x == 0) {
    int s0 = wsum[0], s1 = wsum[1], s2 = wsum[2], s3 = wsum[3];
    wsum[0] = 0; wsum[1] = s0; wsum[2] = s0 + s1; wsum[3] = s0 + s1 + s2;
    bbase = atomicAdd(gctr, s0 + s1 + s2 + s3);
  }
  __syncthreads();
  if (i < n) {
    int st = bbase + wsum[wid] + (sc - v);
    start[i] = st;
    seg[i] = make_int2(st, v);
    if (v > thresh) {
      int k = atomicAdd(ovfcnt, 1);
      if (k < OVF_CAP) ovf[k] = i;
    }
  }
}

__global__ __launch_bounds__(256) void csr_fill(
    const int* __restrict__ node_idx, const int* __restrict__ hedge_idx,
    const int* __restrict__ startN, const int* __restrict__ startH,
    int* __restrict__ fillN, int* __restrict__ fillH,
    int* __restrict__ pinsN, int* __restrict__ pinsH) {
  int e = blockIdx.x * 256 + threadIdx.x;
  if (e < N_PINS) {
    int n = node_idx[e], h = hedge_idx[e];
    int pH = startH[h] + atomicAdd(&fillH[h], 1);
    pinsH[pH] = n;
    int pN = startN[n] + atomicAdd(&fillN[n], 1);
    pinsN[pN] = h;
  }
}

// ---------------------------------------------------------------------------
// transform (MFMA), as round 2
// ---------------------------------------------------------------------------
__global__ __launch_bounds__(256) void transform_k(
    const ushort_t* __restrict__ xb, const ushort_t* __restrict__ Bsw,
    ushort_t* __restrict__ Vxb, float* __restrict__ lg, int n) {
  __shared__ char Blds[36864];
  __shared__ char Olds[16384];
  int t = threadIdx.x, l = t & 63, w = t >> 6;
  size_t r0 = (size_t)blockIdx.x * 64;
#pragma unroll
  for (int it = 0; it < 9; ++it) {
    int off = it * 4096 + w * 1024 + l * 16;
    gload16((const char*)Bsw + off, Blds + off);
  }
  __syncthreads();

  f32x4 acc[9];
#pragma unroll
  for (int ct = 0; ct < 9; ++ct) acc[ct] = (f32x4){0.f, 0.f, 0.f, 0.f};
  int swz = (l & 7) << 4;
  int lbase = (l & 15) * 256 + (l >> 4) * 16;
  const ushort_t* abase = xb + (r0 + w * 16 + (l & 15)) * 128 + (l >> 4) * 8;
#pragma unroll
  for (int kk = 0; kk < 4; ++kk) {
    bf16x8 a = *(const bf16x8*)(abase + kk * 32);
#pragma unroll
    for (int ct = 0; ct < 9; ++ct) {
      bf16x8 b = *(const bf16x8*)(Blds + ((ct * 4096 + kk * 64 + lbase) ^ swz));
      acc[ct] = __builtin_amdgcn_mfma_f32_16x16x32_bf16(a, b, acc[ct], 0, 0, 0);
    }
  }
  if ((l & 15) < 4) {
    size_t rb = r0 + w * 16 + (l >> 4) * 4;
#pragma unroll
    for (int j = 0; j < 4; ++j) lg[(rb + j) * 4 + (l & 15)] = acc[8][j];
  }
  int row64 = w * 16 + (l >> 4) * 4;
#pragma unroll
  for (int ct = 0; ct < 8; ++ct) {
    int c2 = (ct * 16 + (l & 15)) * 2;
#pragma unroll
    for (int j = 0; j < 4; ++j) {
      int r = row64 + j;
      int addr = (r * 256 + c2) ^ ((r & 0xC) << 3);
      *(ushort_t*)(Olds + addr) = f2bf(acc[ct][j]);
    }
  }
  __syncthreads();
#pragma unroll
  for (int it = 0; it < 4; ++it) {
    int L = it * 4096 + t * 16;
    int r = L >> 8;
    int phys = L ^ ((r & 0xC) << 3);
    *(uint4*)((char*)Vxb + r0 * 256 + L) = *(const uint4*)(Olds + phys);
  }
}

// ---------------------------------------------------------------------------
// attention v3: grouped. L lanes per target (G=64/L targets per wave).
// Softmax over <=L pins in one shot (lane li owns pin li of its subgroup);
// per-pin normalized head-weights + row byte-offsets staged in per-wave LDS;
// gather: each lane covers C=128/L cols (one uint4/uint2 per pin = full row
// per subgroup). Fused Q-skip + LN0. Targets with deg > L are skipped and
// handled by trailing fallback blocks via an overflow list (64-wide, any deg).
// ---------------------------------------------------------------------------
template <int L>
__global__ __launch_bounds__(256) void attn_g(
    const ushort_t* __restrict__ Vxb, const float* __restrict__ lg,
    const int2* __restrict__ seg, const int* __restrict__ pins,
    const float* __restrict__ Qflat, const float* __restrict__ g0,
    const float* __restrict__ be0, ushort_t* __restrict__ xmidb, int n_tgt,
    int mainBlocks, const int* __restrict__ ovf, const int* __restrict__ ovfcnt) {
  constexpr int G = 64 / L;    // targets per wave
  constexpr int C = 128 / L;   // bf16 cols per lane
  __shared__ float wl[4][G][L][4];
  __shared__ int pl[4][G][L];
  int wid = threadIdx.x >> 6, lane = threadIdx.x & 63;
  const char* vb = (const char*)Vxb;

  if ((int)blockIdx.x < mainBlocks) {
    int g = lane / L, li = lane % L;
    int tg = ((int)blockIdx.x * 4 + wid) * G + g;
    bool tval = tg < n_tgt;
    int2 sc = tval ? seg[tg] : make_int2(0, 0);
    int base = sc.x, deg = sc.y;
    bool fast = deg <= L;
    int mydeg = (tval && fast) ? deg : 0;
    bool act = li < mydeg;
    int p = act ? pins[base + li] : 0;
    float4 l4;
    if (act) l4 = *(const float4*)(lg + p * 4);
    else l4 = make_float4(-3.4e38f, -3.4e38f, -3.4e38f, -3.4e38f);
    float m0 = l4.x, m1 = l4.y, m2 = l4.z, m3 = l4.w;
#pragma unroll
    for (int off = 1; off < L; off <<= 1) {
      m0 = fmaxf(m0, __shfl_xor(m0, off));
      m1 = fmaxf(m1, __shfl_xor(m1, off));
      m2 = fmaxf(m2, __shfl_xor(m2, off));
      m3 = fmaxf(m3, __shfl_xor(m3, off));
    }
    float e0 = __expf(l4.x - m0), e1 = __expf(l4.y - m1);
    float e2 = __expf(l4.z - m2), e3 = __expf(l4.w - m3);
    float s0 = e0, s1 = e1, s2 = e2, s3 = e3;
#pragma unroll
    for (int off = 1; off < L; off <<= 1) {
      s0 += __shfl_xor(s0, off);
      s1 += __shfl_xor(s1, off);
      s2 += __shfl_xor(s2, off);
      s3 += __shfl_xor(s3, off);
    }
    wl[wid][g][li][0] = e0 / s0;
    wl[wid][g][li][1] = e1 / s1;
    wl[wid][g][li][2] = e2 / s2;
    wl[wid][g][li][3] = e3 / s3;
    pl[wid][g][li] = p << 8;

    int myh = li / (L / 4);  // head owning this lane's cols
    float acc[C];
#pragma unroll
    for (int c = 0; c < C; ++c) acc[c] = 0.f;
    for (int e = 0; e < mydeg; ++e) {
      int off = pl[wid][g][e];
      float wgt = wl[wid][g][e][myh];
      const char* src = vb + off + li * (C * 2);
      unsigned u[C / 2];
      if constexpr (C == 8) {
        uint4 v = *(const uint4*)src;
        u[0] = v.x; u[1] = v.y; u[2] = v.z; u[3] = v.w;
      } else {
        uint2 v = *(const uint2*)src;
        u[0] = v.x; u[1] = v.y;
      }
#pragma unroll
      for (int j = 0; j < C / 2; ++j) {
        acc[2 * j] = fmaf(wgt, __uint_as_float(u[j] << 16), acc[2 * j]);
        acc[2 * j + 1] = fmaf(wgt, __uint_as_float(u[j] & 0xffff0000u), acc[2 * j + 1]);
      }
    }
    // Q-skip + LN0 over this subgroup's L lanes
    float q[C], gv[C], bv[C];
#pragma unroll
    for (int j = 0; j < C / 4; ++j) {
      float4 t = *(const float4*)(Qflat + li * C + j * 4);
      q[j * 4] = t.x; q[j * 4 + 1] = t.y; q[j * 4 + 2] = t.z; q[j * 4 + 3] = t.w;
      t = *(const float4*)(g0 + li * C + j * 4);
      gv[j * 4] = t.x; gv[j * 4 + 1] = t.y; gv[j * 4 + 2] = t.z; gv[j * 4 + 3] = t.w;
      t = *(const float4*)(be0 + li * C + j * 4);
      bv[j * 4] = t.x; bv[j * 4 + 1] = t.y; bv[j * 4 + 2] = t.z; bv[j * 4 + 3] = t.w;
    }
    float t1 = 0.f, t2 = 0.f;
#pragma unroll
    for (int c = 0; c < C; ++c) {
      float x = acc[c] + q[c];
      acc[c] = x;
      t1 += x;
      t2 += x * x;
    }
#pragma unroll
    for (int off = 1; off < L; off <<= 1) {
      t1 += __shfl_xor(t1, off);
      t2 += __shfl_xor(t2, off);
    }
    float mean = t1 * (1.f / 128.f);
    float var = t2 * (1.f / 128.f) - mean * mean;
    float rs = rsqrtf(var + 1e-5f);
    if (tval && fast) {
      float o[C];
#pragma unroll
      for (int c = 0; c < C; ++c) o[c] = (acc[c] - mean) * rs * gv[c] + bv[c];
      char* dst = (char*)xmidb + (size_t)tg * 256 + li * (C * 2);
      if constexpr (C == 8) {
        uint4 pk;
        pk.x = ((unsigned)f2bf(o[1]) << 16) | f2bf(o[0]);
        pk.y = ((unsigned)f2bf(o[3]) << 16) | f2bf(o[2]);
        pk.z = ((unsigned)f2bf(o[5]) << 16) | f2bf(o[4]);
        pk.w = ((unsigned)f2bf(o[7]) << 16) | f2bf(o[6]);
        *(uint4*)dst = pk;
      } else {
        uint2 pk;
        pk.x = ((unsigned)f2bf(o[1]) << 16) | f2bf(o[0]);
        pk.y = ((unsigned)f2bf(o[3]) << 16) | f2bf(o[2]);
        *(uint2*)dst = pk;
      }
    }
    return;
  }

  // ---- overflow fallback: one target per wave, any degree ----
  int cnt = *ovfcnt;
  if (cnt > OVF_CAP) cnt = OVF_CAP;
  int head = lane >> 4;
  for (int idx = ((int)blockIdx.x - mainBlocks) * 4 + wid; idx < cnt; idx += 128) {
    int tg = ovf[idx];
    int2 sc = seg[tg];
    int base = sc.x, deg = sc.y;
    float m0 = -3.4e38f, m1 = -3.4e38f, m2 = -3.4e38f, m3 = -3.4e38f;
    for (int i = lane; i < deg; i += 64) {
      int p = pins[base + i];
      float4 l4 = *(const float4*)(lg + p * 4);
      m0 = fmaxf(m0, l4.x); m1 = fmaxf(m1, l4.y);
      m2 = fmaxf(m2, l4.z); m3 = fmaxf(m3, l4.w);
    }
#pragma unroll
    for (int off = 1; off < 64; off <<= 1) {
      m0 = fmaxf(m0, __shfl_xor(m0, off));
      m1 = fmaxf(m1, __shfl_xor(m1, off));
      m2 = fmaxf(m2, __shfl_xor(m2, off));
      m3 = fmaxf(m3, __shfl_xor(m3, off));
    }
    float s0 = 0.f, s1 = 0.f, s2 = 0.f, s3 = 0.f;
    for (int i = lane; i < deg; i += 64) {
      int p = pins[base + i];
      float4 l4 = *(const float4*)(lg + p * 4);
      s0 += __expf(l4.x - m0); s1 += __expf(l4.y - m1);
      s2 += __expf(l4.z - m2); s3 += __expf(l4.w - m3);
    }
#pragma unroll
    for (int off = 1; off < 64; off <<= 1) {
      s0 += __shfl_xor(s0, off);
      s1 += __shfl_xor(s1, off);
      s2 += __shfl_xor(s2, off);
      s3 += __shfl_xor(s3, off);
    }
    float mh = (head & 2) ? ((head & 1) ? m3 : m2) : ((head & 1) ? m1 : m0);
    float sh = (head & 2) ? ((head & 1) ? s3 : s2) : ((head & 1) ? s1 : s0);
    float rdh = (deg > 0) ? 1.f / sh : 0.f;
    float acc0 = 0.f, acc1 = 0.f;
    for (int e = 0; e < deg; ++e) {
      int p = pins[base + e];
      float w0 = __expf(lg[p * 4 + head] - mh) * rdh;
      unsigned int v = *(const unsigned int*)(vb + (p << 8) + lane * 4);
      acc0 = fmaf(w0, __uint_as_float(v << 16), acc0);
      acc1 = fmaf(w0, __uint_as_float(v & 0xffff0000u), acc1);
    }
    float2 q2 = ((const float2*)Qflat)[lane];
    float x0v = acc0 + q2.x;
    float x1v = acc1 + q2.y;
    float t1 = x0v + x1v, t2 = x0v * x0v + x1v * x1v;
#pragma unroll
    for (int off = 1; off < 64; off <<= 1) {
      t1 += __shfl_xor(t1, off);
      t2 += __shfl_xor(t2, off);
    }
    float mean = t1 * (1.f / 128.f);
    float var = t2 * (1.f / 128.f) - mean * mean;
    float rs = rsqrtf(var + 1e-5f);
    float2 gg = ((const float2*)g0)[lane];
    float2 bb = ((const float2*)be0)[lane];
    float o0 = (x0v - mean) * rs * gg.x + bb.x;
    float o1 = (x1v - mean) * rs * gg.y + bb.y;
    unsigned int pk = ((unsigned int)f2bf(o1) << 16) | f2bf(o0);
    ((unsigned int*)xmidb)[tg * 64 + lane] = pk;
  }
}

// ---------------------------------------------------------------------------
// mlp (MFMA), as round 2
// ---------------------------------------------------------------------------
__global__ __launch_bounds__(256) void mlp_k(
    const ushort_t* __restrict__ xmb, const ushort_t* __restrict__ W1sw,
    const float* __restrict__ b1, const ushort_t* __restrict__ W2sw,
    const float* __restrict__ b2, const float* __restrict__ g1,
    const float* __restrict__ be1, float* __restrict__ outf,
    ushort_t* __restrict__ outb, int n, int wf32) {
  __shared__ char Wlds[32768];
  __shared__ char Hlds[16384];
  int t = threadIdx.x, l = t & 63, w = t >> 6;
  size_t r0 = (size_t)blockIdx.x * 64;
#pragma unroll
  for (int it = 0; it < 8; ++it) {
    int off = it * 4096 + w * 1024 + l * 16;
    gload16((const char*)W1sw + off, Wlds + off);
  }
  float b1v[8], b2v[8], g1v[8], be1v[8];
#pragma unroll
  for (int ct = 0; ct < 8; ++ct) {
    int c = ct * 16 + (l & 15);
    b1v[ct] = b1[c]; b2v[ct] = b2[c]; g1v[ct] = g1[c]; be1v[ct] = be1[c];
  }
  __syncthreads();

  int swz = (l & 7) << 4;
  int lbase = (l & 15) * 256 + (l >> 4) * 16;
  f32x4 acc[8];
#pragma unroll
  for (int ct = 0; ct < 8; ++ct) acc[ct] = (f32x4){b1v[ct], b1v[ct], b1v[ct], b1v[ct]};
  const ushort_t* abase = xmb + (r0 + w * 16 + (l & 15)) * 128 + (l >> 4) * 8;
#pragma unroll
  for (int kk = 0; kk < 4; ++kk) {
    bf16x8 a = *(const bf16x8*)(abase + kk * 32);
#pragma unroll
    for (int ct = 0; ct < 8; ++ct) {
      bf16x8 b = *(const bf16x8*)(Wlds + ((ct * 4096 + kk * 64 + lbase) ^ swz));
      acc[ct] = __builtin_amdgcn_mfma_f32_16x16x32_bf16(a, b, acc[ct], 0, 0, 0);
    }
  }
  int hbase = w * 4096;
#pragma unroll
  for (int ct = 0; ct < 8; ++ct) {
    int c2 = (ct * 16 + (l & 15)) * 2;
#pragma unroll
    for (int j = 0; j < 4; ++j) {
      int rl = (l >> 4) * 4 + j;
      int addr = hbase + ((rl * 256 + c2) ^ ((rl & 7) << 4));
      *(ushort_t*)(Hlds + addr) = f2bf(fmaxf(acc[ct][j], 0.f));
    }
  }
  __syncthreads();
#pragma unroll
  for (int it = 0; it < 8; ++it) {
    int off = it * 4096 + w * 1024 + l * 16;
    gload16((const char*)W2sw + off, Wlds + off);
  }
  __syncthreads();

  f32x4 acc2[8];
#pragma unroll
  for (int ct = 0; ct < 8; ++ct) acc2[ct] = (f32x4){b2v[ct], b2v[ct], b2v[ct], b2v[ct]};
#pragma unroll
  for (int kk = 0; kk < 4; ++kk) {
    bf16x8 a = *(const bf16x8*)(Hlds + (hbase + ((lbase + kk * 64) ^ swz)));
#pragma unroll
    for (int ct = 0; ct < 8; ++ct) {
      bf16x8 b = *(const bf16x8*)(Wlds + ((ct * 4096 + kk * 64 + lbase) ^ swz));
      acc2[ct] = __builtin_amdgcn_mfma_f32_16x16x32_bf16(a, b, acc2[ct], 0, 0, 0);
    }
  }
  size_t rbase = r0 + w * 16 + (l >> 4) * 4;
  float s1[4] = {0.f, 0.f, 0.f, 0.f}, s2[4] = {0.f, 0.f, 0.f, 0.f};
#pragma unroll
  for (int ct = 0; ct < 8; ++ct) {
    int c = ct * 16 + (l & 15);
#pragma unroll
    for (int j = 0; j < 4; ++j) {
      float x = bf2f(xmb[(rbase + j) * 128 + c]);
      float y = acc2[ct][j] + x;
      acc2[ct][j] = y;
      s1[j] += y;
      s2[j] += y * y;
    }
  }
#pragma unroll
  for (int off = 1; off < 16; off <<= 1) {
#pragma unroll
    for (int j = 0; j < 4; ++j) {
      s1[j] += __shfl_xor(s1[j], off);
      s2[j] += __shfl_xor(s2[j], off);
    }
  }
  float mean[4], rs[4];
#pragma unroll
  for (int j = 0; j < 4; ++j) {
    mean[j] = s1[j] * (1.f / 128.f);
    float var = s2[j] * (1.f / 128.f) - mean[j] * mean[j];
    rs[j] = rsqrtf(var + 1e-5f);
  }
#pragma unroll
  for (int ct = 0; ct < 8; ++ct) {
    int c = ct * 16 + (l & 15);
#pragma unroll
    for (int j = 0; j < 4; ++j) {
      float o = fmaxf((acc2[ct][j] - mean[j]) * rs[j] * g1v[ct] + be1v[ct], 0.f);
      size_t row = rbase + j;
      outb[row * 128 + c] = f2bf(o);
      if (wf32 && row < (size_t)n) outf[row * 128 + c] = o;
    }
  }
}

// ---------------------------------------------------------------------------
extern "C" void kernel_launch(void* const* d_in, const int* in_sizes, int n_in,
                              void* d_out, int out_size, void* d_ws, size_t ws_size,
                              hipStream_t stream) {
  const float* x0_in = (const float*)d_in[0];
  const float* Kw  = (const float*)d_in[1];
  const float* Vw  = (const float*)d_in[2];
  const float* Qw  = (const float*)d_in[3];
  const float* W1  = (const float*)d_in[4];
  const float* b1  = (const float*)d_in[5];
  const float* W2  = (const float*)d_in[6];
  const float* b2  = (const float*)d_in[7];
  const float* ln0g = (const float*)d_in[8];
  const float* ln0b = (const float*)d_in[9];
  const float* ln1g = (const float*)d_in[10];
  const float* ln1b = (const float*)d_in[11];
  const int* node_idx  = (const int*)d_in[12];
  const int* hedge_idx = (const int*)d_in[13];

  float* out = (float*)d_out;
  float* x0_out = out;
  float* x1_out = out + (size_t)N_NODES * 128;

  char* w = (char*)d_ws;
  auto alloc = [&](size_t bytes) -> void* {
    void* p = (void*)w;
    w += (bytes + 255) & ~(size_t)255;
    return p;
  };
  ushort_t* Vvqsw = (ushort_t*)alloc(4 * 18432 * 2);
  ushort_t* W1sw  = (ushort_t*)alloc(4 * 16384 * 2);
  ushort_t* W2sw  = (ushort_t*)alloc(4 * 16384 * 2);
  ushort_t* x0b   = (ushort_t*)alloc((size_t)NPN * 128 * 2);
  ushort_t* x1b   = (ushort_t*)alloc((size_t)NPH * 128 * 2);
  ushort_t* Vxb   = (ushort_t*)alloc((size_t)NPN * 128 * 2);
  float*    lg    = (float*)alloc((size_t)NPN * 4 * 4);
  ushort_t* xmidb = (ushort_t*)alloc((size_t)NPN * 128 * 2);
  int* startH = (int*)alloc(N_HEDGES * 4);
  int* startN = (int*)alloc(N_NODES * 4);
  int2* segH  = (int2*)alloc((size_t)N_HEDGES * 8);
  int2* segN  = (int2*)alloc((size_t)N_NODES * 8);
  int* pinsH  = (int*)alloc(N_PINS * 4);
  int* pinsN  = (int*)alloc(N_PINS * 4);
  int* ovfH   = (int*)alloc(OVF_CAP * 4);
  int* ovfN   = (int*)alloc(OVF_CAP * 4);
  int* zbase  = (int*)alloc((size_t)(2 * (N_HEDGES + N_NODES) + 4) * 4);
  int* cntH = zbase;
  int* cntN = cntH + N_HEDGES;
  int* fillH = cntN + N_NODES;
  int* fillN = fillH + N_HEDGES;
  int* gctr = fillN + N_NODES;  // [gctrH, gctrN, ovfcntH, ovfcntN]

  hipMemsetAsync(zbase, 0, (size_t)(2 * (N_HEDGES + N_NODES) + 4) * 4, stream);

  conv_k<<<(N_NODES * 128 / 4 + 255) / 256, 256, 0, stream>>>(x0_in, x0b, N_NODES * 32);
  prep_k<<<288, 256, 0, stream>>>(Kw, Vw, Qw, W1, W2, Vvqsw, W1sw, W2sw);
  csr_count<<<(N_PINS + 255) / 256, 256, 0, stream>>>(node_idx, hedge_idx, cntN, cntH);
  csr_scan<<<(N_HEDGES + 255) / 256, 256, 0, stream>>>(cntH, startH, segH, N_HEDGES,
                                                       gctr + 0, 32, ovfH, gctr + 2);
  csr_scan<<<(N_NODES + 255) / 256, 256, 0, stream>>>(cntN, startN, segN, N_NODES,
                                                      gctr + 1, 16, ovfN, gctr + 3);
  csr_fill<<<(N_PINS + 255) / 256, 256, 0, stream>>>(node_idx, hedge_idx, startN, startH,
                                                     fillN, fillH, pinsN, pinsH);

  const ushort_t* srcs[4] = {x0b, x1b, x0b, x1b};
  int n_srcs[4] = {N_NODES, N_HEDGES, N_NODES, N_HEDGES};
  const int2* segs[4] = {segH, segN, segH, segN};
  const int* pinss[4] = {pinsH, pinsN, pinsH, pinsN};
  int n_tgts[4] = {N_HEDGES, N_NODES, N_HEDGES, N_NODES};
  float* outf[4] = {x1_out, x0_out, x1_out, x0_out};
  ushort_t* outbs[4] = {x1b, x0b, x1b, x0b};
  int wf32[4] = {0, 0, 1, 1};

  const int mbH = (N_HEDGES + 7) / 8;     // L=32: 8 targets/block
  const int mbN = (N_NODES + 15) / 16;    // L=16: 16 targets/block

  for (int b = 0; b < 4; ++b) {
    int n_src = n_srcs[b], n_tgt = n_tgts[b];
    transform_k<<<(n_src + 63) / 64, 256, 0, stream>>>(srcs[b], Vvqsw + b * 18432,
                                                       Vxb, lg, n_src);
    if (b & 1) {
      attn_g<16><<<mbN + 32, 256, 0, stream>>>(Vxb, lg, segs[b], pinss[b],
                                               Qw + b * 128, ln0g + b * 128,
                                               ln0b + b * 128, xmidb, n_tgt,
                                               mbN, ovfN, gctr + 3);
    } else {
      attn_g<32><<<mbH + 32, 256, 0, stream>>>(Vxb, lg, segs[b], pinss[b],
                                               Qw + b * 128, ln0g + b * 128,
                                               ln0b + b * 128, xmidb, n_tgt,
                                               mbH, ovfH, gctr + 2);
    }
    mlp_k<<<(n_tgt + 63) / 64, 256, 0, stream>>>(xmidb, W1sw + b * 16384, b1 + b * 128,
                                                 W2sw + b * 16384, b2 + b * 128,
                                                 ln1g + b * 128, ln1b + b * 128,
                                                 outf[b], outbs[b], n_tgt, wf32[b]);
  }
}

// Round 5
// 289.117 us; speedup vs baseline: 3.6344x; 1.0915x over previous
//
#include <hip/hip_runtime.h>

#define N_NODES 100000
#define N_HEDGES 30000
#define N_PINS 400000
#define NPN 100096   // padded node rows (>= 1563*64)
#define NPH 30080    // padded hedge rows (>= 469*64)
#define OVF_CAP 8192
#define SCAN_BH 118  // ceil(30000/256)
#define SCAN_BN 391  // ceil(100000/256)

typedef __attribute__((ext_vector_type(8))) short bf16x8;
typedef __attribute__((ext_vector_type(4))) float f32x4;
typedef unsigned short ushort_t;

__device__ __forceinline__ unsigned short f2bf(float f) {
  unsigned int u = __float_as_uint(f);
  u += 0x7FFF + ((u >> 16) & 1);
  return (unsigned short)(u >> 16);
}
__device__ __forceinline__ float bf2f(unsigned short s) {
  return __uint_as_float(((unsigned int)s) << 16);
}
__device__ __forceinline__ void gload16(const void* g, void* l) {
  __builtin_amdgcn_global_load_lds(
      (const __attribute__((address_space(1))) unsigned int*)g,
      (__attribute__((address_space(3))) unsigned int*)l, 16, 0, 0);
}

// ---------------------------------------------------------------------------
// fused front-end: x0 f32->bf16 convert  +  pin count (saving ranks)  +
// weight prep (bf16 transposed XOR-swizzled B-matrices). Grid-stride.
// ---------------------------------------------------------------------------
__global__ __launch_bounds__(256) void fused_front(
    const float* __restrict__ x0_in, ushort_t* __restrict__ x0b,
    const int* __restrict__ node_idx, const int* __restrict__ hedge_idx,
    int* __restrict__ cntN, int* __restrict__ cntH, unsigned* __restrict__ rank2,
    const float* __restrict__ Kw, const float* __restrict__ Vw,
    const float* __restrict__ Qw, const float* __restrict__ W1,
    const float* __restrict__ W2, ushort_t* __restrict__ Vvqsw,
    ushort_t* __restrict__ W1sw, ushort_t* __restrict__ W2sw) {
  int gsz = gridDim.x * 256;
  int tid = blockIdx.x * 256 + threadIdx.x;
  // conv: 3.2M floats as 800K float4
  for (int i = tid; i < N_NODES * 32; i += gsz) {
    float4 v = ((const float4*)x0_in)[i];
    ushort_t* p = x0b + (size_t)i * 4;
    p[0] = f2bf(v.x); p[1] = f2bf(v.y); p[2] = f2bf(v.z); p[3] = f2bf(v.w);
  }
  // count + rank capture
  for (int e = tid; e < N_PINS; e += gsz) {
    int n = node_idx[e], h = hedge_idx[e];
    int rn = atomicAdd(&cntN[n], 1);
    int rh = atomicAdd(&cntH[h], 1);
    rank2[e] = ((unsigned)rh << 16) | (unsigned)rn;
  }
  // prep Vv+qvec (144 cols x 128 k per block-mat)
  for (int i = tid; i < 4 * 144 * 128; i += gsz) {
    int b = i / 18432, r = i % 18432, c = r >> 7, d = r & 127;
    float v;
    if (c < 128) {
      v = Vw[((b * 4 + (c >> 5)) * 128 + d) * 32 + (c & 31)];
    } else if (c < 132) {
      int h = c - 128;
      const float* kp = Kw + ((b * 4 + h) * 128 + d) * 32;
      const float* qp = Qw + (b * 4 + h) * 32;
      float s = 0.f;
      for (int k = 0; k < 32; ++k) s += kp[k] * qp[k];
      v = s;
    } else {
      v = 0.f;
    }
    int L = (c * 256 + d * 2) ^ ((c & 7) << 4);
    Vvqsw[b * 18432 + L / 2] = f2bf(v);
  }
  // prep W1/W2 transposed
  for (int i = tid; i < 4 * 128 * 128; i += gsz) {
    int b = i >> 14, r = i & 16383, c = r >> 7, k = r & 127;
    int L = (c * 256 + k * 2) ^ ((c & 7) << 4);
    int idx = b * 16384 + L / 2;
    W1sw[idx] = f2bf(W1[b * 16384 + k * 128 + c]);
    W2sw[idx] = f2bf(W2[b * 16384 + k * 128 + c]);
  }
}

// ---------------------------------------------------------------------------
// merged scan: blocks [0,SCAN_BH) do hedges, rest do nodes.
// gctr layout: [gH, gN, ovfcntH, ovfcntN]
// ---------------------------------------------------------------------------
__global__ __launch_bounds__(256) void csr_scan2(
    const int* __restrict__ cntH, int* __restrict__ startH, int2* __restrict__ segH,
    int* __restrict__ ovfH, const int* __restrict__ cntN, int* __restrict__ startN,
    int2* __restrict__ segN, int* __restrict__ ovfN, int* __restrict__ gctr) {
  __shared__ int wsum[4];
  __shared__ int bbase;
  bool isH = (int)blockIdx.x < SCAN_BH;
  const int* cnt = isH ? cntH : cntN;
  int* start = isH ? startH : startN;
  int2* seg = isH ? segH : segN;
  int* ovf = isH ? ovfH : ovfN;
  int* g = gctr + (isH ? 0 : 1);
  int* oc = gctr + (isH ? 2 : 3);
  int thresh = isH ? 32 : 16;
  int n = isH ? N_HEDGES : N_NODES;
  int i = (isH ? (int)blockIdx.x : (int)blockIdx.x - SCAN_BH) * 256 + threadIdx.x;
  int lane = threadIdx.x & 63, wid = threadIdx.x >> 6;
  int v = (i < n) ? cnt[i] : 0;
  int sc = v;
#pragma unroll
  for (int s = 1; s < 64; s <<= 1) {
    int tv = __shfl_up(sc, s);
    if (lane >= s) sc += tv;
  }
  if (lane == 63) wsum[wid] = sc;
  __syncthreads();
  if (threadIdx.x == 0) {
    int s0 = wsum[0], s1 = wsum[1], s2 = wsum[2], s3 = wsum[3];
    wsum[0] = 0; wsum[1] = s0; wsum[2] = s0 + s1; wsum[3] = s0 + s1 + s2;
    bbase = atomicAdd(g, s0 + s1 + s2 + s3);
  }
  __syncthreads();
  if (i < n) {
    int st = bbase + wsum[wid] + (sc - v);
    start[i] = st;
    seg[i] = make_int2(st, v);
    if (v > thresh) {
      int k = atomicAdd(oc, 1);
      if (k < OVF_CAP) ovf[k] = i;
    }
  }
}

// ---------------------------------------------------------------------------
// fill, atomic-free: slot = start[target] + saved rank
// ---------------------------------------------------------------------------
__global__ __launch_bounds__(256) void csr_fill(
    const int* __restrict__ node_idx, const int* __restrict__ hedge_idx,
    const unsigned* __restrict__ rank2, const int* __restrict__ startN,
    const int* __restrict__ startH, int* __restrict__ pinsN,
    int* __restrict__ pinsH) {
  int e = blockIdx.x * 256 + threadIdx.x;
  if (e < N_PINS) {
    int n = node_idx[e], h = hedge_idx[e];
    unsigned r2 = rank2[e];
    pinsH[startH[h] + (int)(r2 >> 16)] = n;
    pinsN[startN[n] + (int)(r2 & 0xffffu)] = h;
  }
}

// ---------------------------------------------------------------------------
// transform (MFMA): Vxb[n][128] = bf16(x·Vv), lg[n][4] = x·qv.
// ---------------------------------------------------------------------------
__global__ __launch_bounds__(256) void transform_k(
    const ushort_t* __restrict__ xb, const ushort_t* __restrict__ Bsw,
    ushort_t* __restrict__ Vxb, float* __restrict__ lg, int n) {
  __shared__ char Blds[36864];
  __shared__ char Olds[16384];
  int t = threadIdx.x, l = t & 63, w = t >> 6;
  size_t r0 = (size_t)blockIdx.x * 64;
#pragma unroll
  for (int it = 0; it < 9; ++it) {
    int off = it * 4096 + w * 1024 + l * 16;
    gload16((const char*)Bsw + off, Blds + off);
  }
  __syncthreads();

  f32x4 acc[9];
#pragma unroll
  for (int ct = 0; ct < 9; ++ct) acc[ct] = (f32x4){0.f, 0.f, 0.f, 0.f};
  int swz = (l & 7) << 4;
  int lbase = (l & 15) * 256 + (l >> 4) * 16;
  const ushort_t* abase = xb + (r0 + w * 16 + (l & 15)) * 128 + (l >> 4) * 8;
#pragma unroll
  for (int kk = 0; kk < 4; ++kk) {
    bf16x8 a = *(const bf16x8*)(abase + kk * 32);
#pragma unroll
    for (int ct = 0; ct < 9; ++ct) {
      bf16x8 b = *(const bf16x8*)(Blds + ((ct * 4096 + kk * 64 + lbase) ^ swz));
      acc[ct] = __builtin_amdgcn_mfma_f32_16x16x32_bf16(a, b, acc[ct], 0, 0, 0);
    }
  }
  if ((l & 15) < 4) {
    size_t rb = r0 + w * 16 + (l >> 4) * 4;
#pragma unroll
    for (int j = 0; j < 4; ++j) lg[(rb + j) * 4 + (l & 15)] = acc[8][j];
  }
  int row64 = w * 16 + (l >> 4) * 4;
#pragma unroll
  for (int ct = 0; ct < 8; ++ct) {
    int c2 = (ct * 16 + (l & 15)) * 2;
#pragma unroll
    for (int j = 0; j < 4; ++j) {
      int r = row64 + j;
      int addr = (r * 256 + c2) ^ ((r & 0xC) << 3);
      *(ushort_t*)(Olds + addr) = f2bf(acc[ct][j]);
    }
  }
  __syncthreads();
#pragma unroll
  for (int it = 0; it < 4; ++it) {
    int L = it * 4096 + t * 16;
    int r = L >> 8;
    int phys = L ^ ((r & 0xC) << 3);
    *(uint4*)((char*)Vxb + r0 * 256 + L) = *(const uint4*)(Olds + phys);
  }
}

// ---------------------------------------------------------------------------
// attention (grouped, as round 4): L lanes per target.
// ---------------------------------------------------------------------------
template <int L>
__global__ __launch_bounds__(256) void attn_g(
    const ushort_t* __restrict__ Vxb, const float* __restrict__ lg,
    const int2* __restrict__ seg, const int* __restrict__ pins,
    const float* __restrict__ Qflat, const float* __restrict__ g0,
    const float* __restrict__ be0, ushort_t* __restrict__ xmidb, int n_tgt,
    int mainBlocks, const int* __restrict__ ovf, const int* __restrict__ ovfcnt) {
  constexpr int G = 64 / L;
  constexpr int C = 128 / L;
  __shared__ float wl[4][G][L][4];
  __shared__ int pl[4][G][L];
  int wid = threadIdx.x >> 6, lane = threadIdx.x & 63;
  const char* vb = (const char*)Vxb;

  if ((int)blockIdx.x < mainBlocks) {
    int g = lane / L, li = lane % L;
    int tg = ((int)blockIdx.x * 4 + wid) * G + g;
    bool tval = tg < n_tgt;
    int2 sc = tval ? seg[tg] : make_int2(0, 0);
    int base = sc.x, deg = sc.y;
    bool fast = deg <= L;
    int mydeg = (tval && fast) ? deg : 0;
    bool act = li < mydeg;
    int p = act ? pins[base + li] : 0;
    float4 l4;
    if (act) l4 = *(const float4*)(lg + p * 4);
    else l4 = make_float4(-3.4e38f, -3.4e38f, -3.4e38f, -3.4e38f);
    float m0 = l4.x, m1 = l4.y, m2 = l4.z, m3 = l4.w;
#pragma unroll
    for (int off = 1; off < L; off <<= 1) {
      m0 = fmaxf(m0, __shfl_xor(m0, off));
      m1 = fmaxf(m1, __shfl_xor(m1, off));
      m2 = fmaxf(m2, __shfl_xor(m2, off));
      m3 = fmaxf(m3, __shfl_xor(m3, off));
    }
    float e0 = __expf(l4.x - m0), e1 = __expf(l4.y - m1);
    float e2 = __expf(l4.z - m2), e3 = __expf(l4.w - m3);
    float s0 = e0, s1 = e1, s2 = e2, s3 = e3;
#pragma unroll
    for (int off = 1; off < L; off <<= 1) {
      s0 += __shfl_xor(s0, off);
      s1 += __shfl_xor(s1, off);
      s2 += __shfl_xor(s2, off);
      s3 += __shfl_xor(s3, off);
    }
    wl[wid][g][li][0] = e0 / s0;
    wl[wid][g][li][1] = e1 / s1;
    wl[wid][g][li][2] = e2 / s2;
    wl[wid][g][li][3] = e3 / s3;
    pl[wid][g][li] = p << 8;

    int myh = li / (L / 4);
    float acc[C];
#pragma unroll
    for (int c = 0; c < C; ++c) acc[c] = 0.f;
    for (int e = 0; e < mydeg; ++e) {
      int off = pl[wid][g][e];
      float wgt = wl[wid][g][e][myh];
      const char* src = vb + off + li * (C * 2);
      unsigned u[C / 2];
      if constexpr (C == 8) {
        uint4 v = *(const uint4*)src;
        u[0] = v.x; u[1] = v.y; u[2] = v.z; u[3] = v.w;
      } else {
        uint2 v = *(const uint2*)src;
        u[0] = v.x; u[1] = v.y;
      }
#pragma unroll
      for (int j = 0; j < C / 2; ++j) {
        acc[2 * j] = fmaf(wgt, __uint_as_float(u[j] << 16), acc[2 * j]);
        acc[2 * j + 1] = fmaf(wgt, __uint_as_float(u[j] & 0xffff0000u), acc[2 * j + 1]);
      }
    }
    float q[C], gv[C], bv[C];
#pragma unroll
    for (int j = 0; j < C / 4; ++j) {
      float4 t = *(const float4*)(Qflat + li * C + j * 4);
      q[j * 4] = t.x; q[j * 4 + 1] = t.y; q[j * 4 + 2] = t.z; q[j * 4 + 3] = t.w;
      t = *(const float4*)(g0 + li * C + j * 4);
      gv[j * 4] = t.x; gv[j * 4 + 1] = t.y; gv[j * 4 + 2] = t.z; gv[j * 4 + 3] = t.w;
      t = *(const float4*)(be0 + li * C + j * 4);
      bv[j * 4] = t.x; bv[j * 4 + 1] = t.y; bv[j * 4 + 2] = t.z; bv[j * 4 + 3] = t.w;
    }
    float t1 = 0.f, t2 = 0.f;
#pragma unroll
    for (int c = 0; c < C; ++c) {
      float x = acc[c] + q[c];
      acc[c] = x;
      t1 += x;
      t2 += x * x;
    }
#pragma unroll
    for (int off = 1; off < L; off <<= 1) {
      t1 += __shfl_xor(t1, off);
      t2 += __shfl_xor(t2, off);
    }
    float mean = t1 * (1.f / 128.f);
    float var = t2 * (1.f / 128.f) - mean * mean;
    float rs = rsqrtf(var + 1e-5f);
    if (tval && fast) {
      float o[C];
#pragma unroll
      for (int c = 0; c < C; ++c) o[c] = (acc[c] - mean) * rs * gv[c] + bv[c];
      char* dst = (char*)xmidb + (size_t)tg * 256 + li * (C * 2);
      if constexpr (C == 8) {
        uint4 pk;
        pk.x = ((unsigned)f2bf(o[1]) << 16) | f2bf(o[0]);
        pk.y = ((unsigned)f2bf(o[3]) << 16) | f2bf(o[2]);
        pk.z = ((unsigned)f2bf(o[5]) << 16) | f2bf(o[4]);
        pk.w = ((unsigned)f2bf(o[7]) << 16) | f2bf(o[6]);
        *(uint4*)dst = pk;
      } else {
        uint2 pk;
        pk.x = ((unsigned)f2bf(o[1]) << 16) | f2bf(o[0]);
        pk.y = ((unsigned)f2bf(o[3]) << 16) | f2bf(o[2]);
        *(uint2*)dst = pk;
      }
    }
    return;
  }

  // overflow fallback: one target per wave, any degree
  int cnt = *ovfcnt;
  if (cnt > OVF_CAP) cnt = OVF_CAP;
  int head = lane >> 4;
  for (int idx = ((int)blockIdx.x - mainBlocks) * 4 + wid; idx < cnt; idx += 128) {
    int tg = ovf[idx];
    int2 sc = seg[tg];
    int base = sc.x, deg = sc.y;
    float m0 = -3.4e38f, m1 = -3.4e38f, m2 = -3.4e38f, m3 = -3.4e38f;
    for (int i = lane; i < deg; i += 64) {
      int p = pins[base + i];
      float4 l4 = *(const float4*)(lg + p * 4);
      m0 = fmaxf(m0, l4.x); m1 = fmaxf(m1, l4.y);
      m2 = fmaxf(m2, l4.z); m3 = fmaxf(m3, l4.w);
    }
#pragma unroll
    for (int off = 1; off < 64; off <<= 1) {
      m0 = fmaxf(m0, __shfl_xor(m0, off));
      m1 = fmaxf(m1, __shfl_xor(m1, off));
      m2 = fmaxf(m2, __shfl_xor(m2, off));
      m3 = fmaxf(m3, __shfl_xor(m3, off));
    }
    float s0 = 0.f, s1 = 0.f, s2 = 0.f, s3 = 0.f;
    for (int i = lane; i < deg; i += 64) {
      int p = pins[base + i];
      float4 l4 = *(const float4*)(lg + p * 4);
      s0 += __expf(l4.x - m0); s1 += __expf(l4.y - m1);
      s2 += __expf(l4.z - m2); s3 += __expf(l4.w - m3);
    }
#pragma unroll
    for (int off = 1; off < 64; off <<= 1) {
      s0 += __shfl_xor(s0, off);
      s1 += __shfl_xor(s1, off);
      s2 += __shfl_xor(s2, off);
      s3 += __shfl_xor(s3, off);
    }
    float mh = (head & 2) ? ((head & 1) ? m3 : m2) : ((head & 1) ? m1 : m0);
    float sh = (head & 2) ? ((head & 1) ? s3 : s2) : ((head & 1) ? s1 : s0);
    float rdh = (deg > 0) ? 1.f / sh : 0.f;
    float acc0 = 0.f, acc1 = 0.f;
    for (int e = 0; e < deg; ++e) {
      int p = pins[base + e];
      float w0 = __expf(lg[p * 4 + head] - mh) * rdh;
      unsigned int v = *(const unsigned int*)(vb + (p << 8) + lane * 4);
      acc0 = fmaf(w0, __uint_as_float(v << 16), acc0);
      acc1 = fmaf(w0, __uint_as_float(v & 0xffff0000u), acc1);
    }
    float2 q2 = ((const float2*)Qflat)[lane];
    float x0v = acc0 + q2.x;
    float x1v = acc1 + q2.y;
    float t1 = x0v + x1v, t2 = x0v * x0v + x1v * x1v;
#pragma unroll
    for (int off = 1; off < 64; off <<= 1) {
      t1 += __shfl_xor(t1, off);
      t2 += __shfl_xor(t2, off);
    }
    float mean = t1 * (1.f / 128.f);
    float var = t2 * (1.f / 128.f) - mean * mean;
    float rs = rsqrtf(var + 1e-5f);
    float2 gg = ((const float2*)g0)[lane];
    float2 bb = ((const float2*)be0)[lane];
    float o0 = (x0v - mean) * rs * gg.x + bb.x;
    float o1 = (x1v - mean) * rs * gg.y + bb.y;
    unsigned int pk = ((unsigned int)f2bf(o1) << 16) | f2bf(o0);
    ((unsigned int*)xmidb)[tg * 64 + lane] = pk;
  }
}

// ---------------------------------------------------------------------------
// mlp (MFMA). flags: bit0 = write f32 out, bit1 = write bf16 outb
// ---------------------------------------------------------------------------
__global__ __launch_bounds__(256) void mlp_k(
    const ushort_t* __restrict__ xmb, const ushort_t* __restrict__ W1sw,
    const float* __restrict__ b1, const ushort_t* __restrict__ W2sw,
    const float* __restrict__ b2, const float* __restrict__ g1,
    const float* __restrict__ be1, float* __restrict__ outf,
    ushort_t* __restrict__ outb, int n, int flags) {
  __shared__ char Wlds[32768];
  __shared__ char Hlds[16384];
  int t = threadIdx.x, l = t & 63, w = t >> 6;
  size_t r0 = (size_t)blockIdx.x * 64;
#pragma unroll
  for (int it = 0; it < 8; ++it) {
    int off = it * 4096 + w * 1024 + l * 16;
    gload16((const char*)W1sw + off, Wlds + off);
  }
  float b1v[8], b2v[8], g1v[8], be1v[8];
#pragma unroll
  for (int ct = 0; ct < 8; ++ct) {
    int c = ct * 16 + (l & 15);
    b1v[ct] = b1[c]; b2v[ct] = b2[c]; g1v[ct] = g1[c]; be1v[ct] = be1[c];
  }
  __syncthreads();

  int swz = (l & 7) << 4;
  int lbase = (l & 15) * 256 + (l >> 4) * 16;
  f32x4 acc[8];
#pragma unroll
  for (int ct = 0; ct < 8; ++ct) acc[ct] = (f32x4){b1v[ct], b1v[ct], b1v[ct], b1v[ct]};
  const ushort_t* abase = xmb + (r0 + w * 16 + (l & 15)) * 128 + (l >> 4) * 8;
#pragma unroll
  for (int kk = 0; kk < 4; ++kk) {
    bf16x8 a = *(const bf16x8*)(abase + kk * 32);
#pragma unroll
    for (int ct = 0; ct < 8; ++ct) {
      bf16x8 b = *(const bf16x8*)(Wlds + ((ct * 4096 + kk * 64 + lbase) ^ swz));
      acc[ct] = __builtin_amdgcn_mfma_f32_16x16x32_bf16(a, b, acc[ct], 0, 0, 0);
    }
  }
  int hbase = w * 4096;
#pragma unroll
  for (int ct = 0; ct < 8; ++ct) {
    int c2 = (ct * 16 + (l & 15)) * 2;
#pragma unroll
    for (int j = 0; j < 4; ++j) {
      int rl = (l >> 4) * 4 + j;
      int addr = hbase + ((rl * 256 + c2) ^ ((rl & 7) << 4));
      *(ushort_t*)(Hlds + addr) = f2bf(fmaxf(acc[ct][j], 0.f));
    }
  }
  __syncthreads();
#pragma unroll
  for (int it = 0; it < 8; ++it) {
    int off = it * 4096 + w * 1024 + l * 16;
    gload16((const char*)W2sw + off, Wlds + off);
  }
  __syncthreads();

  f32x4 acc2[8];
#pragma unroll
  for (int ct = 0; ct < 8; ++ct) acc2[ct] = (f32x4){b2v[ct], b2v[ct], b2v[ct], b2v[ct]};
#pragma unroll
  for (int kk = 0; kk < 4; ++kk) {
    bf16x8 a = *(const bf16x8*)(Hlds + (hbase + ((lbase + kk * 64) ^ swz)));
#pragma unroll
    for (int ct = 0; ct < 8; ++ct) {
      bf16x8 b = *(const bf16x8*)(Wlds + ((ct * 4096 + kk * 64 + lbase) ^ swz));
      acc2[ct] = __builtin_amdgcn_mfma_f32_16x16x32_bf16(a, b, acc2[ct], 0, 0, 0);
    }
  }
  size_t rbase = r0 + w * 16 + (l >> 4) * 4;
  float s1[4] = {0.f, 0.f, 0.f, 0.f}, s2[4] = {0.f, 0.f, 0.f, 0.f};
#pragma unroll
  for (int ct = 0; ct < 8; ++ct) {
    int c = ct * 16 + (l & 15);
#pragma unroll
    for (int j = 0; j < 4; ++j) {
      float x = bf2f(xmb[(rbase + j) * 128 + c]);
      float y = acc2[ct][j] + x;
      acc2[ct][j] = y;
      s1[j] += y;
      s2[j] += y * y;
    }
  }
#pragma unroll
  for (int off = 1; off < 16; off <<= 1) {
#pragma unroll
    for (int j = 0; j < 4; ++j) {
      s1[j] += __shfl_xor(s1[j], off);
      s2[j] += __shfl_xor(s2[j], off);
    }
  }
  float mean[4], rs[4];
#pragma unroll
  for (int j = 0; j < 4; ++j) {
    mean[j] = s1[j] * (1.f / 128.f);
    float var = s2[j] * (1.f / 128.f) - mean[j] * mean[j];
    rs[j] = rsqrtf(var + 1e-5f);
  }
#pragma unroll
  for (int ct = 0; ct < 8; ++ct) {
    int c = ct * 16 + (l & 15);
#pragma unroll
    for (int j = 0; j < 4; ++j) {
      float o = fmaxf((acc2[ct][j] - mean[j]) * rs[j] * g1v[ct] + be1v[ct], 0.f);
      size_t row = rbase + j;
      if (flags & 2) outb[row * 128 + c] = f2bf(o);
      if ((flags & 1) && row < (size_t)n) outf[row * 128 + c] = o;
    }
  }
}

// ---------------------------------------------------------------------------
extern "C" void kernel_launch(void* const* d_in, const int* in_sizes, int n_in,
                              void* d_out, int out_size, void* d_ws, size_t ws_size,
                              hipStream_t stream) {
  const float* x0_in = (const float*)d_in[0];
  const float* Kw  = (const float*)d_in[1];
  const float* Vw  = (const float*)d_in[2];
  const float* Qw  = (const float*)d_in[3];
  const float* W1  = (const float*)d_in[4];
  const float* b1  = (const float*)d_in[5];
  const float* W2  = (const float*)d_in[6];
  const float* b2  = (const float*)d_in[7];
  const float* ln0g = (const float*)d_in[8];
  const float* ln0b = (const float*)d_in[9];
  const float* ln1g = (const float*)d_in[10];
  const float* ln1b = (const float*)d_in[11];
  const int* node_idx  = (const int*)d_in[12];
  const int* hedge_idx = (const int*)d_in[13];

  float* out = (float*)d_out;
  float* x0_out = out;
  float* x1_out = out + (size_t)N_NODES * 128;

  char* w = (char*)d_ws;
  auto alloc = [&](size_t bytes) -> void* {
    void* p = (void*)w;
    w += (bytes + 255) & ~(size_t)255;
    return p;
  };
  ushort_t* Vvqsw = (ushort_t*)alloc(4 * 18432 * 2);
  ushort_t* W1sw  = (ushort_t*)alloc(4 * 16384 * 2);
  ushort_t* W2sw  = (ushort_t*)alloc(4 * 16384 * 2);
  ushort_t* x0b   = (ushort_t*)alloc((size_t)NPN * 128 * 2);
  ushort_t* x1b   = (ushort_t*)alloc((size_t)NPH * 128 * 2);
  ushort_t* Vxb   = (ushort_t*)alloc((size_t)NPN * 128 * 2);
  float*    lg    = (float*)alloc((size_t)NPN * 4 * 4);
  ushort_t* xmidb = (ushort_t*)alloc((size_t)NPN * 128 * 2);
  int* startH = (int*)alloc(N_HEDGES * 4);
  int* startN = (int*)alloc(N_NODES * 4);
  int2* segH  = (int2*)alloc((size_t)N_HEDGES * 8);
  int2* segN  = (int2*)alloc((size_t)N_NODES * 8);
  int* pinsH  = (int*)alloc(N_PINS * 4);
  int* pinsN  = (int*)alloc(N_PINS * 4);
  int* ovfH   = (int*)alloc(OVF_CAP * 4);
  int* ovfN   = (int*)alloc(OVF_CAP * 4);
  unsigned* rank2 = (unsigned*)alloc((size_t)N_PINS * 4);
  int* zbase  = (int*)alloc((size_t)(N_HEDGES + N_NODES + 4) * 4);
  int* cntH = zbase;
  int* cntN = cntH + N_HEDGES;
  int* gctr = cntN + N_NODES;  // [gH, gN, ovfcntH, ovfcntN]

  hipMemsetAsync(zbase, 0, (size_t)(N_HEDGES + N_NODES + 4) * 4, stream);

  fused_front<<<1024, 256, 0, stream>>>(x0_in, x0b, node_idx, hedge_idx, cntN, cntH,
                                        rank2, Kw, Vw, Qw, W1, W2, Vvqsw, W1sw, W2sw);
  csr_scan2<<<SCAN_BH + SCAN_BN, 256, 0, stream>>>(cntH, startH, segH, ovfH,
                                                   cntN, startN, segN, ovfN, gctr);
  csr_fill<<<(N_PINS + 255) / 256, 256, 0, stream>>>(node_idx, hedge_idx, rank2,
                                                     startN, startH, pinsN, pinsH);

  const ushort_t* srcs[4] = {x0b, x1b, x0b, x1b};
  int n_srcs[4] = {N_NODES, N_HEDGES, N_NODES, N_HEDGES};
  const int2* segs[4] = {segH, segN, segH, segN};
  const int* pinss[4] = {pinsH, pinsN, pinsH, pinsN};
  int n_tgts[4] = {N_HEDGES, N_NODES, N_HEDGES, N_NODES};
  float* outf[4] = {x1_out, x0_out, x1_out, x0_out};
  ushort_t* outbs[4] = {x1b, x0b, x1b, x0b};
  int flags[4] = {2, 2, 3, 1};  // b3: f32 only (x0b dead afterwards)

  const int mbH = (N_HEDGES + 7) / 8;     // L=32: 8 targets/block
  const int mbN = (N_NODES + 15) / 16;    // L=16: 16 targets/block

  for (int b = 0; b < 4; ++b) {
    int n_src = n_srcs[b], n_tgt = n_tgts[b];
    transform_k<<<(n_src + 63) / 64, 256, 0, stream>>>(srcs[b], Vvqsw + b * 18432,
                                                       Vxb, lg, n_src);
    if (b & 1) {
      attn_g<16><<<mbN + 32, 256, 0, stream>>>(Vxb, lg, segs[b], pinss[b],
                                               Qw + b * 128, ln0g + b * 128,
                                               ln0b + b * 128, xmidb, n_tgt,
                                               mbN, ovfN, gctr + 3);
    } else {
      attn_g<32><<<mbH + 32, 256, 0, stream>>>(Vxb, lg, segs[b], pinss[b],
                                               Qw + b * 128, ln0g + b * 128,
                                               ln0b + b * 128, xmidb, n_tgt,
                                               mbH, ovfH, gctr + 2);
    }
    mlp_k<<<(n_tgt + 63) / 64, 256, 0, stream>>>(xmidb, W1sw + b * 16384, b1 + b * 128,
                                                 W2sw + b * 16384, b2 + b * 128,
                                                 ln1g + b * 128, ln1b + b * 128,
                                                 outf[b], outbs[b], n_tgt, flags[b]);
  }
}

// Round 7
// 287.792 us; speedup vs baseline: 3.6511x; 1.0046x over previous
//
#include <hip/hip_runtime.h>

#define N_NODES 100000
#define N_HEDGES 30000
#define N_PINS 400000
#define NPN 100096   // padded node rows
#define NPH 30080    // padded hedge rows
#define OVF_CAP 8192
#define SCAN_BH 118  // ceil(30000/256)
#define SCAN_BN 391  // ceil(100000/256)

typedef __attribute__((ext_vector_type(8))) short bf16x8;
typedef __attribute__((ext_vector_type(4))) float f32x4;
typedef unsigned short ushort_t;

__device__ __forceinline__ unsigned short f2bf(float f) {
  unsigned int u = __float_as_uint(f);
  u += 0x7FFF + ((u >> 16) & 1);
  return (unsigned short)(u >> 16);
}
__device__ __forceinline__ float bf2f(unsigned short s) {
  return __uint_as_float(((unsigned int)s) << 16);
}
__device__ __forceinline__ void gload16(const void* g, void* l) {
  __builtin_amdgcn_global_load_lds(
      (const __attribute__((address_space(1))) unsigned int*)g,
      (__attribute__((address_space(3))) unsigned int*)l, 16, 0, 0);
}

// ---------------------------------------------------------------------------
// fused front-end (round-6 version, semantics == round-5 pieces):
// atomics issued FIRST (latency hidden under streaming), rank2 written LAST;
// vectorized conv (8 bf16 per uint4 store); weight prep.
// ---------------------------------------------------------------------------
__global__ __launch_bounds__(256) void fused_front(
    const float* __restrict__ x0_in, ushort_t* __restrict__ x0b,
    const int* __restrict__ node_idx, const int* __restrict__ hedge_idx,
    int* __restrict__ cntN, int* __restrict__ cntH, unsigned* __restrict__ rank2,
    const float* __restrict__ Kw, const float* __restrict__ Vw,
    const float* __restrict__ Qw, const float* __restrict__ W1,
    const float* __restrict__ W2, ushort_t* __restrict__ Vvqsw,
    ushort_t* __restrict__ W1sw, ushort_t* __restrict__ W2sw) {
  int gsz = gridDim.x * 256;
  int tid = blockIdx.x * 256 + threadIdx.x;
  int rn = 0, rh = 0;
  bool hasPin = tid < N_PINS;
  if (hasPin) {
    int n_i = node_idx[tid], h_i = hedge_idx[tid];
    rn = atomicAdd(&cntN[n_i], 1);
    rh = atomicAdd(&cntH[h_i], 1);
  }
  for (int i = tid; i < N_NODES * 16; i += gsz) {
    const float4* s = (const float4*)x0_in + (size_t)i * 2;
    float4 a = s[0], b = s[1];
    uint4 o;
    o.x = ((unsigned)f2bf(a.y) << 16) | f2bf(a.x);
    o.y = ((unsigned)f2bf(a.w) << 16) | f2bf(a.z);
    o.z = ((unsigned)f2bf(b.y) << 16) | f2bf(b.x);
    o.w = ((unsigned)f2bf(b.w) << 16) | f2bf(b.z);
    ((uint4*)x0b)[i] = o;
  }
  for (int i = tid; i < 4 * 144 * 128; i += gsz) {
    int b = i / 18432, r = i % 18432, c = r >> 7, d = r & 127;
    float v;
    if (c < 128) {
      v = Vw[((b * 4 + (c >> 5)) * 128 + d) * 32 + (c & 31)];
    } else if (c < 132) {
      int h = c - 128;
      const float* kp = Kw + ((b * 4 + h) * 128 + d) * 32;
      const float* qp = Qw + (b * 4 + h) * 32;
      float s = 0.f;
      for (int k = 0; k < 32; ++k) s += kp[k] * qp[k];
      v = s;
    } else {
      v = 0.f;
    }
    int L = (c * 256 + d * 2) ^ ((c & 7) << 4);
    Vvqsw[b * 18432 + L / 2] = f2bf(v);
  }
  for (int i = tid; i < 4 * 128 * 128; i += gsz) {
    int b = i >> 14, r = i & 16383, c = r >> 7, k = r & 127;
    int L = (c * 256 + k * 2) ^ ((c & 7) << 4);
    int idx = b * 16384 + L / 2;
    W1sw[idx] = f2bf(W1[b * 16384 + k * 128 + c]);
    W2sw[idx] = f2bf(W2[b * 16384 + k * 128 + c]);
  }
  if (hasPin) rank2[tid] = ((unsigned)rh << 16) | (unsigned)rn;
}

// ---------------------------------------------------------------------------
// merged scan (with overflow detection restored): blocks [0,SCAN_BH) hedges,
// rest nodes. gctr: [gH, gN, ovfcntH, ovfcntN]
// ---------------------------------------------------------------------------
__global__ __launch_bounds__(256) void csr_scan2(
    const int* __restrict__ cntH, int2* __restrict__ segH, int* __restrict__ ovfH,
    const int* __restrict__ cntN, int2* __restrict__ segN, int* __restrict__ ovfN,
    int* __restrict__ gctr) {
  __shared__ int wsum[4];
  __shared__ int bbase;
  bool isH = (int)blockIdx.x < SCAN_BH;
  const int* cnt = isH ? cntH : cntN;
  int2* seg = isH ? segH : segN;
  int* ovf = isH ? ovfH : ovfN;
  int* g = gctr + (isH ? 0 : 1);
  int* oc = gctr + (isH ? 2 : 3);
  int thresh = isH ? 32 : 16;
  int n = isH ? N_HEDGES : N_NODES;
  int i = (isH ? (int)blockIdx.x : (int)blockIdx.x - SCAN_BH) * 256 + threadIdx.x;
  int lane = threadIdx.x & 63, wid = threadIdx.x >> 6;
  int v = (i < n) ? cnt[i] : 0;
  int sc = v;
#pragma unroll
  for (int s = 1; s < 64; s <<= 1) {
    int tv = __shfl_up(sc, s);
    if (lane >= s) sc += tv;
  }
  if (lane == 63) wsum[wid] = sc;
  __syncthreads();
  if (threadIdx.x == 0) {
    int s0 = wsum[0], s1 = wsum[1], s2 = wsum[2], s3 = wsum[3];
    wsum[0] = 0; wsum[1] = s0; wsum[2] = s0 + s1; wsum[3] = s0 + s1 + s2;
    bbase = atomicAdd(g, s0 + s1 + s2 + s3);
  }
  __syncthreads();
  if (i < n) {
    int st = bbase + wsum[wid] + (sc - v);
    seg[i] = make_int2(st, v);
    if (v > thresh) {
      int k = atomicAdd(oc, 1);
      if (k < OVF_CAP) ovf[k] = i;
    }
  }
}

// ---------------------------------------------------------------------------
// fill, atomic-free: slot = seg[target].x + saved rank
// ---------------------------------------------------------------------------
__global__ __launch_bounds__(256) void csr_fill(
    const int* __restrict__ node_idx, const int* __restrict__ hedge_idx,
    const unsigned* __restrict__ rank2, const int2* __restrict__ segN,
    const int2* __restrict__ segH, int* __restrict__ pinsN,
    int* __restrict__ pinsH) {
  int e = blockIdx.x * 256 + threadIdx.x;
  if (e < N_PINS) {
    int n = node_idx[e], h = hedge_idx[e];
    unsigned r2 = rank2[e];
    pinsH[segH[h].x + (int)(r2 >> 16)] = n;
    pinsN[segN[n].x + (int)(r2 & 0xffffu)] = h;
  }
}

// ---------------------------------------------------------------------------
// transform (MFMA), proven since round 2
// ---------------------------------------------------------------------------
__global__ __launch_bounds__(256) void transform_k(
    const ushort_t* __restrict__ xb, const ushort_t* __restrict__ Bsw,
    ushort_t* __restrict__ Vxb, float* __restrict__ lg, int n) {
  __shared__ char Blds[36864];
  __shared__ char Olds[16384];
  int t = threadIdx.x, l = t & 63, w = t >> 6;
  size_t r0 = (size_t)blockIdx.x * 64;
#pragma unroll
  for (int it = 0; it < 9; ++it) {
    int off = it * 4096 + w * 1024 + l * 16;
    gload16((const char*)Bsw + off, Blds + off);
  }
  __syncthreads();

  f32x4 acc[9];
#pragma unroll
  for (int ct = 0; ct < 9; ++ct) acc[ct] = (f32x4){0.f, 0.f, 0.f, 0.f};
  int swz = (l & 7) << 4;
  int lbase = (l & 15) * 256 + (l >> 4) * 16;
  const ushort_t* abase = xb + (r0 + w * 16 + (l & 15)) * 128 + (l >> 4) * 8;
#pragma unroll
  for (int kk = 0; kk < 4; ++kk) {
    bf16x8 a = *(const bf16x8*)(abase + kk * 32);
#pragma unroll
    for (int ct = 0; ct < 9; ++ct) {
      bf16x8 b = *(const bf16x8*)(Blds + ((ct * 4096 + kk * 64 + lbase) ^ swz));
      acc[ct] = __builtin_amdgcn_mfma_f32_16x16x32_bf16(a, b, acc[ct], 0, 0, 0);
    }
  }
  if ((l & 15) < 4) {
    size_t rb = r0 + w * 16 + (l >> 4) * 4;
#pragma unroll
    for (int j = 0; j < 4; ++j) lg[(rb + j) * 4 + (l & 15)] = acc[8][j];
  }
  int row64 = w * 16 + (l >> 4) * 4;
#pragma unroll
  for (int ct = 0; ct < 8; ++ct) {
    int c2 = (ct * 16 + (l & 15)) * 2;
#pragma unroll
    for (int j = 0; j < 4; ++j) {
      int r = row64 + j;
      int addr = (r * 256 + c2) ^ ((r & 0xC) << 3);
      *(ushort_t*)(Olds + addr) = f2bf(acc[ct][j]);
    }
  }
  __syncthreads();
#pragma unroll
  for (int it = 0; it < 4; ++it) {
    int L = it * 4096 + t * 16;
    int r = L >> 8;
    int phys = L ^ ((r & 0xC) << 3);
    *(uint4*)((char*)Vxb + r0 * 256 + L) = *(const uint4*)(Olds + phys);
  }
}

// ---------------------------------------------------------------------------
// attention (round-5 PROVEN version): grouped, L lanes per target, one-shot
// softmax for deg<=L, overflow list fallback for deg>L.
// ---------------------------------------------------------------------------
template <int L>
__global__ __launch_bounds__(256) void attn_g(
    const ushort_t* __restrict__ Vxb, const float* __restrict__ lg,
    const int2* __restrict__ seg, const int* __restrict__ pins,
    const float* __restrict__ Qflat, const float* __restrict__ g0,
    const float* __restrict__ be0, ushort_t* __restrict__ xmidb, int n_tgt,
    int mainBlocks, const int* __restrict__ ovf, const int* __restrict__ ovfcnt) {
  constexpr int G = 64 / L;
  constexpr int C = 128 / L;
  __shared__ float wl[4][G][L][4];
  __shared__ int pl[4][G][L];
  int wid = threadIdx.x >> 6, lane = threadIdx.x & 63;
  const char* vb = (const char*)Vxb;

  if ((int)blockIdx.x < mainBlocks) {
    int g = lane / L, li = lane % L;
    int tg = ((int)blockIdx.x * 4 + wid) * G + g;
    bool tval = tg < n_tgt;
    int2 sc = tval ? seg[tg] : make_int2(0, 0);
    int base = sc.x, deg = sc.y;
    bool fast = deg <= L;
    int mydeg = (tval && fast) ? deg : 0;
    bool act = li < mydeg;
    int p = act ? pins[base + li] : 0;
    float4 l4;
    if (act) l4 = *(const float4*)(lg + p * 4);
    else l4 = make_float4(-3.4e38f, -3.4e38f, -3.4e38f, -3.4e38f);
    float m0 = l4.x, m1 = l4.y, m2 = l4.z, m3 = l4.w;
#pragma unroll
    for (int off = 1; off < L; off <<= 1) {
      m0 = fmaxf(m0, __shfl_xor(m0, off));
      m1 = fmaxf(m1, __shfl_xor(m1, off));
      m2 = fmaxf(m2, __shfl_xor(m2, off));
      m3 = fmaxf(m3, __shfl_xor(m3, off));
    }
    float e0 = __expf(l4.x - m0), e1 = __expf(l4.y - m1);
    float e2 = __expf(l4.z - m2), e3 = __expf(l4.w - m3);
    float s0 = e0, s1 = e1, s2 = e2, s3 = e3;
#pragma unroll
    for (int off = 1; off < L; off <<= 1) {
      s0 += __shfl_xor(s0, off);
      s1 += __shfl_xor(s1, off);
      s2 += __shfl_xor(s2, off);
      s3 += __shfl_xor(s3, off);
    }
    wl[wid][g][li][0] = e0 / s0;
    wl[wid][g][li][1] = e1 / s1;
    wl[wid][g][li][2] = e2 / s2;
    wl[wid][g][li][3] = e3 / s3;
    pl[wid][g][li] = p << 8;

    int myh = li / (L / 4);
    float acc[C];
#pragma unroll
    for (int c = 0; c < C; ++c) acc[c] = 0.f;
    for (int e = 0; e < mydeg; ++e) {
      int off = pl[wid][g][e];
      float wgt = wl[wid][g][e][myh];
      const char* src = vb + off + li * (C * 2);
      unsigned u[C / 2];
      if constexpr (C == 8) {
        uint4 v = *(const uint4*)src;
        u[0] = v.x; u[1] = v.y; u[2] = v.z; u[3] = v.w;
      } else {
        uint2 v = *(const uint2*)src;
        u[0] = v.x; u[1] = v.y;
      }
#pragma unroll
      for (int j = 0; j < C / 2; ++j) {
        acc[2 * j] = fmaf(wgt, __uint_as_float(u[j] << 16), acc[2 * j]);
        acc[2 * j + 1] = fmaf(wgt, __uint_as_float(u[j] & 0xffff0000u), acc[2 * j + 1]);
      }
    }
    float q[C], gv[C], bv[C];
#pragma unroll
    for (int j = 0; j < C / 4; ++j) {
      float4 t = *(const float4*)(Qflat + li * C + j * 4);
      q[j * 4] = t.x; q[j * 4 + 1] = t.y; q[j * 4 + 2] = t.z; q[j * 4 + 3] = t.w;
      t = *(const float4*)(g0 + li * C + j * 4);
      gv[j * 4] = t.x; gv[j * 4 + 1] = t.y; gv[j * 4 + 2] = t.z; gv[j * 4 + 3] = t.w;
      t = *(const float4*)(be0 + li * C + j * 4);
      bv[j * 4] = t.x; bv[j * 4 + 1] = t.y; bv[j * 4 + 2] = t.z; bv[j * 4 + 3] = t.w;
    }
    float t1 = 0.f, t2 = 0.f;
#pragma unroll
    for (int c = 0; c < C; ++c) {
      float x = acc[c] + q[c];
      acc[c] = x;
      t1 += x;
      t2 += x * x;
    }
#pragma unroll
    for (int off = 1; off < L; off <<= 1) {
      t1 += __shfl_xor(t1, off);
      t2 += __shfl_xor(t2, off);
    }
    float mean = t1 * (1.f / 128.f);
    float var = t2 * (1.f / 128.f) - mean * mean;
    float rs = rsqrtf(var + 1e-5f);
    if (tval && fast) {
      float o[C];
#pragma unroll
      for (int c = 0; c < C; ++c) o[c] = (acc[c] - mean) * rs * gv[c] + bv[c];
      char* dst = (char*)xmidb + (size_t)tg * 256 + li * (C * 2);
      if constexpr (C == 8) {
        uint4 pk;
        pk.x = ((unsigned)f2bf(o[1]) << 16) | f2bf(o[0]);
        pk.y = ((unsigned)f2bf(o[3]) << 16) | f2bf(o[2]);
        pk.z = ((unsigned)f2bf(o[5]) << 16) | f2bf(o[4]);
        pk.w = ((unsigned)f2bf(o[7]) << 16) | f2bf(o[6]);
        *(uint4*)dst = pk;
      } else {
        uint2 pk;
        pk.x = ((unsigned)f2bf(o[1]) << 16) | f2bf(o[0]);
        pk.y = ((unsigned)f2bf(o[3]) << 16) | f2bf(o[2]);
        *(uint2*)dst = pk;
      }
    }
    return;
  }

  // overflow fallback: one target per wave, any degree
  int cnt = *ovfcnt;
  if (cnt > OVF_CAP) cnt = OVF_CAP;
  int head = lane >> 4;
  for (int idx = ((int)blockIdx.x - mainBlocks) * 4 + wid; idx < cnt; idx += 128) {
    int tg = ovf[idx];
    int2 sc = seg[tg];
    int base = sc.x, deg = sc.y;
    float m0 = -3.4e38f, m1 = -3.4e38f, m2 = -3.4e38f, m3 = -3.4e38f;
    for (int i = lane; i < deg; i += 64) {
      int p = pins[base + i];
      float4 l4 = *(const float4*)(lg + p * 4);
      m0 = fmaxf(m0, l4.x); m1 = fmaxf(m1, l4.y);
      m2 = fmaxf(m2, l4.z); m3 = fmaxf(m3, l4.w);
    }
#pragma unroll
    for (int off = 1; off < 64; off <<= 1) {
      m0 = fmaxf(m0, __shfl_xor(m0, off));
      m1 = fmaxf(m1, __shfl_xor(m1, off));
      m2 = fmaxf(m2, __shfl_xor(m2, off));
      m3 = fmaxf(m3, __shfl_xor(m3, off));
    }
    float s0 = 0.f, s1 = 0.f, s2 = 0.f, s3 = 0.f;
    for (int i = lane; i < deg; i += 64) {
      int p = pins[base + i];
      float4 l4 = *(const float4*)(lg + p * 4);
      s0 += __expf(l4.x - m0); s1 += __expf(l4.y - m1);
      s2 += __expf(l4.z - m2); s3 += __expf(l4.w - m3);
    }
#pragma unroll
    for (int off = 1; off < 64; off <<= 1) {
      s0 += __shfl_xor(s0, off);
      s1 += __shfl_xor(s1, off);
      s2 += __shfl_xor(s2, off);
      s3 += __shfl_xor(s3, off);
    }
    float mh = (head & 2) ? ((head & 1) ? m3 : m2) : ((head & 1) ? m1 : m0);
    float sh = (head & 2) ? ((head & 1) ? s3 : s2) : ((head & 1) ? s1 : s0);
    float rdh = (deg > 0) ? 1.f / sh : 0.f;
    float acc0 = 0.f, acc1 = 0.f;
    for (int e = 0; e < deg; ++e) {
      int p = pins[base + e];
      float w0 = __expf(lg[p * 4 + head] - mh) * rdh;
      unsigned int v = *(const unsigned int*)(vb + (p << 8) + lane * 4);
      acc0 = fmaf(w0, __uint_as_float(v << 16), acc0);
      acc1 = fmaf(w0, __uint_as_float(v & 0xffff0000u), acc1);
    }
    float2 q2 = ((const float2*)Qflat)[lane];
    float x0v = acc0 + q2.x;
    float x1v = acc1 + q2.y;
    float t1 = x0v + x1v, t2 = x0v * x0v + x1v * x1v;
#pragma unroll
    for (int off = 1; off < 64; off <<= 1) {
      t1 += __shfl_xor(t1, off);
      t2 += __shfl_xor(t2, off);
    }
    float mean = t1 * (1.f / 128.f);
    float var = t2 * (1.f / 128.f) - mean * mean;
    float rs = rsqrtf(var + 1e-5f);
    float2 gg = ((const float2*)g0)[lane];
    float2 bb = ((const float2*)be0)[lane];
    float o0 = (x0v - mean) * rs * gg.x + bb.x;
    float o1 = (x1v - mean) * rs * gg.y + bb.y;
    unsigned int pk = ((unsigned int)f2bf(o1) << 16) | f2bf(o0);
    ((unsigned int*)xmidb)[tg * 64 + lane] = pk;
  }
}

// ---------------------------------------------------------------------------
// mlp (MFMA, round-5 proven). flags: bit0 = f32 out, bit1 = bf16 outb
// ---------------------------------------------------------------------------
__global__ __launch_bounds__(256) void mlp_k(
    const ushort_t* __restrict__ xmb, const ushort_t* __restrict__ W1sw,
    const float* __restrict__ b1, const ushort_t* __restrict__ W2sw,
    const float* __restrict__ b2, const float* __restrict__ g1,
    const float* __restrict__ be1, float* __restrict__ outf,
    ushort_t* __restrict__ outb, int n, int flags) {
  __shared__ char Wlds[32768];
  __shared__ char Hlds[16384];
  int t = threadIdx.x, l = t & 63, w = t >> 6;
  size_t r0 = (size_t)blockIdx.x * 64;
#pragma unroll
  for (int it = 0; it < 8; ++it) {
    int off = it * 4096 + w * 1024 + l * 16;
    gload16((const char*)W1sw + off, Wlds + off);
  }
  float b1v[8], b2v[8], g1v[8], be1v[8];
#pragma unroll
  for (int ct = 0; ct < 8; ++ct) {
    int c = ct * 16 + (l & 15);
    b1v[ct] = b1[c]; b2v[ct] = b2[c]; g1v[ct] = g1[c]; be1v[ct] = be1[c];
  }
  __syncthreads();

  int swz = (l & 7) << 4;
  int lbase = (l & 15) * 256 + (l >> 4) * 16;
  f32x4 acc[8];
#pragma unroll
  for (int ct = 0; ct < 8; ++ct) acc[ct] = (f32x4){b1v[ct], b1v[ct], b1v[ct], b1v[ct]};
  const ushort_t* abase = xmb + (r0 + w * 16 + (l & 15)) * 128 + (l >> 4) * 8;
#pragma unroll
  for (int kk = 0; kk < 4; ++kk) {
    bf16x8 a = *(const bf16x8*)(abase + kk * 32);
#pragma unroll
    for (int ct = 0; ct < 8; ++ct) {
      bf16x8 b = *(const bf16x8*)(Wlds + ((ct * 4096 + kk * 64 + lbase) ^ swz));
      acc[ct] = __builtin_amdgcn_mfma_f32_16x16x32_bf16(a, b, acc[ct], 0, 0, 0);
    }
  }
  int hbase = w * 4096;
#pragma unroll
  for (int ct = 0; ct < 8; ++ct) {
    int c2 = (ct * 16 + (l & 15)) * 2;
#pragma unroll
    for (int j = 0; j < 4; ++j) {
      int rl = (l >> 4) * 4 + j;
      int addr = hbase + ((rl * 256 + c2) ^ ((rl & 7) << 4));
      *(ushort_t*)(Hlds + addr) = f2bf(fmaxf(acc[ct][j], 0.f));
    }
  }
  __syncthreads();
#pragma unroll
  for (int it = 0; it < 8; ++it) {
    int off = it * 4096 + w * 1024 + l * 16;
    gload16((const char*)W2sw + off, Wlds + off);
  }
  __syncthreads();

  f32x4 acc2[8];
#pragma unroll
  for (int ct = 0; ct < 8; ++ct) acc2[ct] = (f32x4){b2v[ct], b2v[ct], b2v[ct], b2v[ct]};
#pragma unroll
  for (int kk = 0; kk < 4; ++kk) {
    bf16x8 a = *(const bf16x8*)(Hlds + (hbase + ((lbase + kk * 64) ^ swz)));
#pragma unroll
    for (int ct = 0; ct < 8; ++ct) {
      bf16x8 b = *(const bf16x8*)(Wlds + ((ct * 4096 + kk * 64 + lbase) ^ swz));
      acc2[ct] = __builtin_amdgcn_mfma_f32_16x16x32_bf16(a, b, acc2[ct], 0, 0, 0);
    }
  }
  size_t rbase = r0 + w * 16 + (l >> 4) * 4;
  float s1[4] = {0.f, 0.f, 0.f, 0.f}, s2[4] = {0.f, 0.f, 0.f, 0.f};
#pragma unroll
  for (int ct = 0; ct < 8; ++ct) {
    int c = ct * 16 + (l & 15);
#pragma unroll
    for (int j = 0; j < 4; ++j) {
      float x = bf2f(xmb[(rbase + j) * 128 + c]);
      float y = acc2[ct][j] + x;
      acc2[ct][j] = y;
      s1[j] += y;
      s2[j] += y * y;
    }
  }
#pragma unroll
  for (int off = 1; off < 16; off <<= 1) {
#pragma unroll
    for (int j = 0; j < 4; ++j) {
      s1[j] += __shfl_xor(s1[j], off);
      s2[j] += __shfl_xor(s2[j], off);
    }
  }
  float mean[4], rs[4];
#pragma unroll
  for (int j = 0; j < 4; ++j) {
    mean[j] = s1[j] * (1.f / 128.f);
    float var = s2[j] * (1.f / 128.f) - mean[j] * mean[j];
    rs[j] = rsqrtf(var + 1e-5f);
  }
#pragma unroll
  for (int ct = 0; ct < 8; ++ct) {
    int c = ct * 16 + (l & 15);
#pragma unroll
    for (int j = 0; j < 4; ++j) {
      float o = fmaxf((acc2[ct][j] - mean[j]) * rs[j] * g1v[ct] + be1v[ct], 0.f);
      size_t row = rbase + j;
      if (flags & 2) outb[row * 128 + c] = f2bf(o);
      if ((flags & 1) && row < (size_t)n) outf[row * 128 + c] = o;
    }
  }
}

// ---------------------------------------------------------------------------
extern "C" void kernel_launch(void* const* d_in, const int* in_sizes, int n_in,
                              void* d_out, int out_size, void* d_ws, size_t ws_size,
                              hipStream_t stream) {
  const float* x0_in = (const float*)d_in[0];
  const float* Kw  = (const float*)d_in[1];
  const float* Vw  = (const float*)d_in[2];
  const float* Qw  = (const float*)d_in[3];
  const float* W1  = (const float*)d_in[4];
  const float* b1  = (const float*)d_in[5];
  const float* W2  = (const float*)d_in[6];
  const float* b2  = (const float*)d_in[7];
  const float* ln0g = (const float*)d_in[8];
  const float* ln0b = (const float*)d_in[9];
  const float* ln1g = (const float*)d_in[10];
  const float* ln1b = (const float*)d_in[11];
  const int* node_idx  = (const int*)d_in[12];
  const int* hedge_idx = (const int*)d_in[13];

  float* out = (float*)d_out;
  float* x0_out = out;
  float* x1_out = out + (size_t)N_NODES * 128;

  char* w = (char*)d_ws;
  auto alloc = [&](size_t bytes) -> void* {
    void* p = (void*)w;
    w += (bytes + 255) & ~(size_t)255;
    return p;
  };
  ushort_t* Vvqsw = (ushort_t*)alloc(4 * 18432 * 2);
  ushort_t* W1sw  = (ushort_t*)alloc(4 * 16384 * 2);
  ushort_t* W2sw  = (ushort_t*)alloc(4 * 16384 * 2);
  ushort_t* x0b   = (ushort_t*)alloc((size_t)NPN * 128 * 2);
  ushort_t* x1b   = (ushort_t*)alloc((size_t)NPH * 128 * 2);
  ushort_t* Vxb   = (ushort_t*)alloc((size_t)NPN * 128 * 2);
  float*    lg    = (float*)alloc((size_t)NPN * 4 * 4);
  ushort_t* xmidb = (ushort_t*)alloc((size_t)NPN * 128 * 2);
  int2* segH  = (int2*)alloc((size_t)N_HEDGES * 8);
  int2* segN  = (int2*)alloc((size_t)N_NODES * 8);
  int* pinsH  = (int*)alloc(N_PINS * 4);
  int* pinsN  = (int*)alloc(N_PINS * 4);
  int* ovfH   = (int*)alloc(OVF_CAP * 4);
  int* ovfN   = (int*)alloc(OVF_CAP * 4);
  unsigned* rank2 = (unsigned*)alloc((size_t)N_PINS * 4);
  int* zbase  = (int*)alloc((size_t)(N_HEDGES + N_NODES + 4) * 4);
  int* cntH = zbase;
  int* cntN = cntH + N_HEDGES;
  int* gctr = cntN + N_NODES;  // [gH, gN, ovfcntH, ovfcntN]

  hipMemsetAsync(zbase, 0, (size_t)(N_HEDGES + N_NODES + 4) * 4, stream);

  fused_front<<<2048, 256, 0, stream>>>(x0_in, x0b, node_idx, hedge_idx, cntN, cntH,
                                        rank2, Kw, Vw, Qw, W1, W2, Vvqsw, W1sw, W2sw);
  csr_scan2<<<SCAN_BH + SCAN_BN, 256, 0, stream>>>(cntH, segH, ovfH,
                                                   cntN, segN, ovfN, gctr);
  csr_fill<<<(N_PINS + 255) / 256, 256, 0, stream>>>(node_idx, hedge_idx, rank2,
                                                     segN, segH, pinsN, pinsH);

  const ushort_t* srcs[4] = {x0b, x1b, x0b, x1b};
  int n_srcs[4] = {N_NODES, N_HEDGES, N_NODES, N_HEDGES};
  const int2* segs[4] = {segH, segN, segH, segN};
  const int* pinss[4] = {pinsH, pinsN, pinsH, pinsN};
  int n_tgts[4] = {N_HEDGES, N_NODES, N_HEDGES, N_NODES};
  float* outf[4] = {x1_out, x0_out, x1_out, x0_out};
  ushort_t* outbs[4] = {x1b, x0b, x1b, x0b};
  int flags[4] = {2, 2, 3, 1};  // b3: f32 only (x0b dead afterwards)

  const int mbH = (N_HEDGES + 7) / 8;     // L=32: 8 targets/block
  const int mbN = (N_NODES + 15) / 16;    // L=16: 16 targets/block

  for (int b = 0; b < 4; ++b) {
    int n_src = n_srcs[b], n_tgt = n_tgts[b];
    transform_k<<<(n_src + 63) / 64, 256, 0, stream>>>(srcs[b], Vvqsw + b * 18432,
                                                       Vxb, lg, n_src);
    if (b & 1) {
      attn_g<16><<<mbN + 32, 256, 0, stream>>>(Vxb, lg, segs[b], pinss[b],
                                               Qw + b * 128, ln0g + b * 128,
                                               ln0b + b * 128, xmidb, n_tgt,
                                               mbN, ovfN, gctr + 3);
    } else {
      attn_g<32><<<mbH + 32, 256, 0, stream>>>(Vxb, lg, segs[b], pinss[b],
                                               Qw + b * 128, ln0g + b * 128,
                                               ln0b + b * 128, xmidb, n_tgt,
                                               mbH, ovfH, gctr + 2);
    }
    mlp_k<<<(n_tgt + 63) / 64, 256, 0, stream>>>(xmidb, W1sw + b * 16384, b1 + b * 128,
                                                 W2sw + b * 16384, b2 + b * 128,
                                                 ln1g + b * 128, ln1b + b * 128,
                                                 outf[b], outbs[b], n_tgt, flags[b]);
  }
}